// Round 1
// 13835.814 us; speedup vs baseline: 1.5702x; 1.5702x over previous
//
#include <hip/hip_runtime.h>
#include <stdint.h>

typedef short s16x8 __attribute__((ext_vector_type(8)));
typedef float f32x4 __attribute__((ext_vector_type(4)));
typedef unsigned short u16;
typedef unsigned long long u64;

#define DEV static __device__ __forceinline__
#define SCOPE_AGENT __HIP_MEMORY_SCOPE_AGENT

DEV u16 f2bf(float f) {
  unsigned u = __float_as_uint(f);
  u = (u + 0x7FFFu + ((u >> 16) & 1u)) >> 16;   // RNE
  return (u16)u;
}
DEV float sigf(float x) { return 1.0f / (1.0f + __expf(-x)); }
DEV float tanh_(float x) { float e = __expf(2.0f * x); return 1.0f - 2.0f / (e + 1.0f); }
DEV f32x4 MFMA(s16x8 a, s16x8 b, f32x4 c) {
  return __builtin_amdgcn_mfma_f32_16x16x32_bf16(a, b, c, 0, 0, 0);
}
// relaxed agent-scope atomics: cache-bypassing (sc0 sc1), per-location coherent.
DEV u64 cload(const u64* p) {
  return __hip_atomic_load((u64*)p, __ATOMIC_RELAXED, SCOPE_AGENT);
}
DEV void cstore(u64* p, u64 v) {
  __hip_atomic_store(p, v, __ATOMIC_RELAXED, SCOPE_AGENT);
}
union U16x8 { u64 u[2]; s16x8 v; };

// ---------------- problem dims ----------------
constexpr int Bz = 256, INz = 512, Hz = 1024, Oz = 128;
constexpr int G4 = 4096;     // 4*H
constexpr int TB = 512;      // beat timesteps (M*S)
constexpr int BM = 8192;     // B*M rows

// ---------------- workspace layout (bytes) ----------------
constexpr size_t OFF_XG   = 0;                                   // f32 [8192][4096]
constexpr size_t OFF_LATB = OFF_XG   + (size_t)BM * G4 * 4;      // bf16 [8192][512]
constexpr size_t OFF_INPB = OFF_LATB + (size_t)BM * INz * 2;     // bf16 [256*512][128]
constexpr size_t OFF_MWIH = OFF_INPB + (size_t)Bz * TB * Oz * 2; // bf16 [4096][512]
constexpr size_t OFF_MWHH = OFF_MWIH + (size_t)G4 * INz * 2;     // bf16 [4096][1024]
constexpr size_t OFF_BWA  = OFF_MWHH + (size_t)G4 * Hz * 2;      // bf16 [4096][1024]
constexpr size_t OFF_BWB  = OFF_BWA  + (size_t)G4 * Hz * 2;      // bf16 [4096][128]
constexpr size_t OFF_BWHH = OFF_BWB  + (size_t)G4 * Oz * 2;      // bf16 [4096][1024]
constexpr size_t OFF_LINW = OFF_BWHH + (size_t)G4 * Hz * 2;      // bf16 [128][1024]
constexpr size_t OFF_LAT  = OFF_LINW + (size_t)Oz * Hz * 2;      // bf16 [8192][1024]
constexpr size_t OFF_HM   = OFF_LAT  + (size_t)BM * Hz * 2;      // bf16 2x[256][1024]
constexpr size_t OFF_HB   = OFF_HM   + (size_t)2 * Bz * Hz * 2;  // bf16 2x[256][1024]
constexpr size_t OFF_RING = OFF_HB   + (size_t)2 * Bz * Hz * 2;  // bf16 [32][256][1024]
constexpr size_t OFF_CTR  = OFF_RING + (size_t)32 * Bz * Hz * 2; // counters (512 u32 = 2KB)

// ================= prep: casts / splits / zeroing =================
__global__ __launch_bounds__(256) void prep_kernel(
    char* __restrict__ ws, const float* __restrict__ latent,
    const float* __restrict__ inputs, const float* __restrict__ mWih,
    const float* __restrict__ mWhh, const float* __restrict__ bWih,
    const float* __restrict__ bWhh, const float* __restrict__ linW)
{
  size_t i = (size_t)blockIdx.x * 256 + threadIdx.x;
  const size_t n0 = (size_t)BM * INz;
  const size_t n1 = (size_t)Bz * TB * Oz;
  const size_t n2 = (size_t)G4 * INz;
  const size_t n3 = (size_t)G4 * Hz;
  const size_t n4 = (size_t)G4 * (Hz + Oz);
  const size_t n5 = (size_t)G4 * Hz;
  const size_t n6 = (size_t)Oz * Hz;
  const size_t n7 = (size_t)2 * Bz * Hz;
  const size_t n8 = (size_t)2 * Bz * Hz;
  const size_t n9 = 512;
  if (i < n0) { ((u16*)(ws + OFF_LATB))[i] = f2bf(latent[i]); return; } i -= n0;
  if (i < n1) { ((u16*)(ws + OFF_INPB))[i] = f2bf(inputs[i]); return; } i -= n1;
  if (i < n2) { ((u16*)(ws + OFF_MWIH))[i] = f2bf(mWih[i]);   return; } i -= n2;
  if (i < n3) { ((u16*)(ws + OFF_MWHH))[i] = f2bf(mWhh[i]);   return; } i -= n3;
  if (i < n4) {
    size_t r = i / 1152, c = i - r * 1152;
    float v = bWih[i];
    if (c < 1024) ((u16*)(ws + OFF_BWA))[r * 1024 + c] = f2bf(v);
    else          ((u16*)(ws + OFF_BWB))[r * 128 + (c - 1024)] = f2bf(v);
    return;
  } i -= n4;
  if (i < n5) { ((u16*)(ws + OFF_BWHH))[i] = f2bf(bWhh[i]);   return; } i -= n5;
  if (i < n6) { ((u16*)(ws + OFF_LINW))[i] = f2bf(linW[i]);   return; } i -= n6;
  if (i < n7) { ((u16*)(ws + OFF_HM))[i] = 0; return; } i -= n7;
  if (i < n8) { ((u16*)(ws + OFF_HB))[i] = 0; return; } i -= n8;
  if (i < n9) { ((unsigned*)(ws + OFF_CTR))[i] = 0; return; }
}

// ================= projection GEMM: C[M][N](f32) = A[M][K](bf16) @ B[N][K]^T + bias =================
__global__ __launch_bounds__(256) void gemm_bt_bias(
    const u16* __restrict__ A, const u16* __restrict__ Bw,
    const float* __restrict__ bias, float* __restrict__ C, int K, int Ndim)
{
  __shared__ u16 As[128 * 40];
  __shared__ u16 Bs[128 * 40];
  const int bx = blockIdx.x & 63;
  const int by = blockIdx.x >> 6;
  const int m0 = bx * 128, n0 = by * 128;
  const int tid = threadIdx.x, lane = tid & 63, wave = tid >> 6;
  const int quad = lane >> 4, l15 = lane & 15;
  const int wm = wave & 1, wn = wave >> 1;
  const int srow = tid >> 1, shalf = tid & 1;

  f32x4 acc[4][4];
  #pragma unroll
  for (int mi = 0; mi < 4; ++mi)
    #pragma unroll
    for (int ni = 0; ni < 4; ++ni) { f32x4 z = {0.f,0.f,0.f,0.f}; acc[mi][ni] = z; }

  const int KC = K >> 5;
  for (int kc = 0; kc < KC; ++kc) {
    const size_t ka = (size_t)(m0 + srow) * K + kc * 32 + shalf * 16;
    s16x8 va0 = *(const s16x8*)(A + ka);
    s16x8 va1 = *(const s16x8*)(A + ka + 8);
    const size_t kb = (size_t)(n0 + srow) * K + kc * 32 + shalf * 16;
    s16x8 vb0 = *(const s16x8*)(Bw + kb);
    s16x8 vb1 = *(const s16x8*)(Bw + kb + 8);
    __syncthreads();
    *(s16x8*)(As + srow * 40 + shalf * 16)     = va0;
    *(s16x8*)(As + srow * 40 + shalf * 16 + 8) = va1;
    *(s16x8*)(Bs + srow * 40 + shalf * 16)     = vb0;
    *(s16x8*)(Bs + srow * 40 + shalf * 16 + 8) = vb1;
    __syncthreads();
    s16x8 af[4], bf[4];
    #pragma unroll
    for (int mi = 0; mi < 4; ++mi)
      af[mi] = *(const s16x8*)(As + (wm * 64 + mi * 16 + l15) * 40 + quad * 8);
    #pragma unroll
    for (int ni = 0; ni < 4; ++ni)
      bf[ni] = *(const s16x8*)(Bs + (wn * 64 + ni * 16 + l15) * 40 + quad * 8);
    #pragma unroll
    for (int mi = 0; mi < 4; ++mi)
      #pragma unroll
      for (int ni = 0; ni < 4; ++ni)
        acc[mi][ni] = MFMA(af[mi], bf[ni], acc[mi][ni]);
  }
  #pragma unroll
  for (int mi = 0; mi < 4; ++mi)
    #pragma unroll
    for (int ni = 0; ni < 4; ++ni) {
      const int col = n0 + wn * 64 + ni * 16 + l15;
      const float bs = bias[col];
      #pragma unroll
      for (int r = 0; r < 4; ++r) {
        const int row = m0 + wm * 64 + mi * 16 + quad * 4 + r;
        C[(size_t)row * Ndim + col] = acc[mi][ni][r] + bs;
      }
    }
}

// ---- duty output projection for one timestep t0 (64 batches x 128 out, K=1024) ----
DEV void oproj_step(const u16* __restrict__ aux, const u16* __restrict__ linW,
                    const float* __restrict__ linb, float* __restrict__ dout,
                    int bt, int t0, int wave, int quad, int l15)
{
  const u64* Arq = (const u64*)aux + (((size_t)((t0 & 31) * 256 + (bt << 6))) << 8);
  const u64* orp = Arq + ((((size_t)wave << 4) + l15) << 8) + (quad << 1);
  const u16* lp[8];
  #pragma unroll
  for (int nt = 0; nt < 8; ++nt)
    lp[nt] = linW + (((size_t)(nt << 4) + l15) << 10) + (quad << 3);
  f32x4 oacc[8];
  #pragma unroll
  for (int nt = 0; nt < 8; ++nt) { f32x4 z = {0.f,0.f,0.f,0.f}; oacc[nt] = z; }
  U16x8 opf[4];
  #pragma unroll
  for (int g = 0; g < 4; ++g) {
    opf[g].u[0] = cload(orp + (g << 3));
    opf[g].u[1] = cload(orp + (g << 3) + 1);
  }
  #pragma unroll
  for (int kc = 0; kc < 32; ++kc) {
    const s16x8 a = opf[kc & 3].v;
    #pragma unroll
    for (int nt = 0; nt < 8; ++nt) {
      s16x8 b = *(const s16x8*)(lp[nt] + (kc << 5));
      oacc[nt] = MFMA(a, b, oacc[nt]);
    }
    if (kc < 28) {
      opf[kc & 3].u[0] = cload(orp + ((kc + 4) << 3));
      opf[kc & 3].u[1] = cload(orp + ((kc + 4) << 3) + 1);
    }
  }
  #pragma unroll
  for (int nt = 0; nt < 8; ++nt) {
    const int col = (nt << 4) + l15;
    const float bs = linb[col];
    #pragma unroll
    for (int r = 0; r < 4; ++r) {
      const int bg2 = (bt << 6) + (wave << 4) + (quad << 2) + r;
      dout[((size_t)bg2 * 512 + t0) * 128 + col] = oacc[nt][r] + bs;
    }
  }
}

// ================= persistent recurrent LSTM =================
// R4 deltas vs R3:
//  - 4 independent 64-block barriers (per batch-tile; all cross-block deps are
//    bt-local): relaxed fetch_add arrive + go-flag broadcast by last arriver,
//    arrive/flag on separate 128B lines, s_sleep(2) backoff. No release/acquire
//    on the hot path (store visibility from the __syncthreads vmcnt drain; h/ring
//    move via cache-bypassing atomics, coherent at LLC).
//  - __launch_bounds__(256,1): LDS already forces 1 block/CU; free the VGPR file
//    (was 96) for pipelining.
//  - h-GEMM: depth-4 kc-group software pipeline (32 cloads in flight vs ~8).
//  - xg loads + beat input-projection hoisted BEFORE the wait (h-independent).
//  - oproj shifted one barrier later (window [t-16, t-1], + post-loop tail),
//    ring-loads pipelined.
template<bool BEAT>
__global__ __launch_bounds__(256, 1) void lstm_rec(
    const u16* __restrict__ Whh,   // [4096][1024] bf16
    const float* __restrict__ xg,  // [8192][4096] f32 rows = b*32 + m
    const u16* __restrict__ WihB,  // [4096][128]  (beat)
    const u16* __restrict__ inp,   // [256*512][128] (beat)
    const u16* __restrict__ linW,  // [128][1024]  (beat)
    const float* __restrict__ linb,// [128]        (beat)
    u16* __restrict__ hbuf0, u16* __restrict__ hbuf1,
    u16* __restrict__ aux,         // measure: lat [8192][1024]; beat: ring [32][256][1024]
    float* __restrict__ dout,      // beat: [256][512][128]
    unsigned* __restrict__ ctr)
{
  extern __shared__ char smem[];
  u16* sW = (u16*)smem;                         // 64 rows x (1024+8)
  float* sEx = (float*)(smem + 64 * 1032 * 2);  // 2 bufs x 64 x 33 floats

  const int blk = blockIdx.x;
  const int bt = blk >> 6, ht = blk & 63;
  const int tid = threadIdx.x;
  const int wave = tid >> 6, lane = tid & 63;
  const int quad = lane >> 4, l15 = lane & 15;
  const int kh = wave & 1, nh = wave >> 1;

  // per-batch-tile barrier: arrive counter and go flag, 128B apart; groups 256B apart
  unsigned* const arr = ctr + (bt << 6);
  unsigned* const flg = arr + 32;

  // stage Whh slice (rows {g*1024 + ht*16 + d}) into LDS, once
  for (int c = tid; c < 8192; c += 256) {
    const int rr = c >> 7;
    const int cc = (c & 127) << 3;
    const int gr = ((rr >> 4) << 10) + (ht << 4) + (rr & 15);
    *(s16x8*)(sW + rr * 1032 + cc) = *(const s16x8*)(Whh + ((size_t)gr << 10) + cc);
  }
  __syncthreads();

  const int batch_l = tid & 63, dgrp = tid >> 6;
  const int b_g = (bt << 6) + batch_l;
  float cst[4] = {0.f, 0.f, 0.f, 0.f};
  float xgv[4][4];

  const int T = BEAT ? 512 : 32;
  const u16* hbufs[2] = {hbuf0, hbuf1};

  for (int t = 0; t < T; ++t) {
    const u16* hp = hbufs[t & 1];
    u16* hn = const_cast<u16*>(hbufs[(t + 1) & 1]);

    // ---------- overlap zone: barrier-independent work ----------
    if (!BEAT || (t & 15) == 0) {   // lat-projection slice (incl. bias), fp32
      const int mrow = BEAT ? (t >> 4) : t;
      const float* xr = xg + (size_t)(b_g * 32 + mrow) * 4096 + (ht << 4) + (dgrp << 2);
      #pragma unroll
      for (int g = 0; g < 4; ++g)
        #pragma unroll
        for (int j = 0; j < 4; ++j) xgv[g][j] = xr[g * 1024 + j];
    }

    f32x4 acc[4][2];
    #pragma unroll
    for (int mi = 0; mi < 4; ++mi)
      #pragma unroll
      for (int gi = 0; gi < 2; ++gi) { f32x4 z = {0.f,0.f,0.f,0.f}; acc[mi][gi] = z; }

    if (BEAT) {  // beat-input projection: inp[:,t,:] @ WihB^T (K=128), h-independent
      #pragma unroll
      for (int kc = 0; kc < 2; ++kc) {
        const int k = (kh << 6) + (kc << 5) + (quad << 3);
        s16x8 bfr0 = *(const s16x8*)(WihB + (size_t)(((nh * 2 + 0) << 10) + (ht << 4) + l15) * 128 + k);
        s16x8 bfr1 = *(const s16x8*)(WihB + (size_t)(((nh * 2 + 1) << 10) + (ht << 4) + l15) * 128 + k);
        #pragma unroll
        for (int mi = 0; mi < 4; ++mi) {
          s16x8 afr = *(const s16x8*)(inp + ((size_t)((bt << 6) + (mi << 4) + l15) * 512 + t) * 128 + k);
          acc[mi][0] = MFMA(afr, bfr0, acc[mi][0]);
          acc[mi][1] = MFMA(afr, bfr1, acc[mi][1]);
        }
      }
    }

    // ---------- wait: all 64 blocks of this bt finished step t-1 ----------
    if (t) {
      if (tid == 0) {
        while (__hip_atomic_load(flg, __ATOMIC_RELAXED, SCOPE_AGENT) < (unsigned)t)
          __builtin_amdgcn_s_sleep(2);
      }
      __syncthreads();
      __atomic_signal_fence(__ATOMIC_SEQ_CST);
    }

    // ---------- duty fused output projection, window [t-16, t-1] ----------
    if (BEAT && t && (t & 15) == 0 && ht < 16)
      oproj_step(aux, linW, linb, dout, bt, t - 16 + ht, wave, quad, l15);

    // ---------- recurrent GEMM: h(t-1) @ Whh^T, depth-4 pipelined ----------
    {
      const u64* hq = (const u64*)hp + ((size_t)(bt << 6) << 8);
      const u64* rp[4];
      #pragma unroll
      for (int mi = 0; mi < 4; ++mi)
        rp[mi] = hq + ((((size_t)(mi << 4)) + l15) << 8) + (kh << 7) + (quad << 1);

      U16x8 pf[4][4];
      #pragma unroll
      for (int g = 0; g < 4; ++g)
        #pragma unroll
        for (int mi = 0; mi < 4; ++mi) {
          pf[g][mi].u[0] = cload(rp[mi] + (g << 3));
          pf[g][mi].u[1] = cload(rp[mi] + (g << 3) + 1);
        }

      const u16* sB0 = sW + (((nh * 2 + 0) << 4) + l15) * 1032 + (kh << 9) + (quad << 3);
      const u16* sB1 = sW + (((nh * 2 + 1) << 4) + l15) * 1032 + (kh << 9) + (quad << 3);
      #pragma unroll
      for (int kc = 0; kc < 16; ++kc) {
        s16x8 bfr0 = *(const s16x8*)(sB0 + (kc << 5));
        s16x8 bfr1 = *(const s16x8*)(sB1 + (kc << 5));
        #pragma unroll
        for (int mi = 0; mi < 4; ++mi) {
          acc[mi][0] = MFMA(pf[kc & 3][mi].v, bfr0, acc[mi][0]);
          acc[mi][1] = MFMA(pf[kc & 3][mi].v, bfr1, acc[mi][1]);
        }
        if (kc < 12) {
          #pragma unroll
          for (int mi = 0; mi < 4; ++mi) {
            pf[kc & 3][mi].u[0] = cload(rp[mi] + ((kc + 4) << 3));
            pf[kc & 3][mi].u[1] = cload(rp[mi] + ((kc + 4) << 3) + 1);
          }
        }
      }
    }

    // ---------- merge k-halves via LDS ----------
    if (kh == 1) {
      #pragma unroll
      for (int mi = 0; mi < 4; ++mi)
        #pragma unroll
        for (int gi = 0; gi < 2; ++gi)
          #pragma unroll
          for (int r = 0; r < 4; ++r)
            sEx[nh * 2112 + ((mi << 4) + (quad << 2) + r) * 33 + (gi << 4) + l15] = acc[mi][gi][r];
    }
    __syncthreads();
    if (kh == 0) {
      #pragma unroll
      for (int mi = 0; mi < 4; ++mi)
        #pragma unroll
        for (int gi = 0; gi < 2; ++gi)
          #pragma unroll
          for (int r = 0; r < 4; ++r) {
            const int idx = nh * 2112 + ((mi << 4) + (quad << 2) + r) * 33 + (gi << 4) + l15;
            sEx[idx] += acc[mi][gi][r];
          }
    }
    __syncthreads();

    // ---------- element-wise LSTM cell update (thread owns 4 dims of 1 batch) ----------
    float hv[4], tv[4];
    {
      const int bo = batch_l * 33;
      #pragma unroll
      for (int j = 0; j < 4; ++j) {
        const int d = (dgrp << 2) + j;
        const float pi = sEx[bo + d]              + xgv[0][j];
        const float pf_ = sEx[bo + 16 + d]        + xgv[1][j];
        const float pg = sEx[2112 + bo + d]       + xgv[2][j];
        const float po = sEx[2112 + bo + 16 + d]  + xgv[3][j];
        const float iv = sigf(pi), fv = sigf(pf_), gv = tanh_(pg), ov = sigf(po);
        cst[j] = fv * cst[j] + iv * gv;
        hv[j] = ov * tanh_(cst[j]);
        tv[j] = tanh_(hv[j]);
      }
    }
    u64 hpk = (u64)f2bf(hv[0]) | ((u64)f2bf(hv[1]) << 16)
            | ((u64)f2bf(hv[2]) << 32) | ((u64)f2bf(hv[3]) << 48);
    u64 tpk = (u64)f2bf(tv[0]) | ((u64)f2bf(tv[1]) << 16)
            | ((u64)f2bf(tv[2]) << 32) | ((u64)f2bf(tv[3]) << 48);
    cstore((u64*)(hn + ((size_t)b_g << 10) + (ht << 4) + (dgrp << 2)), hpk);
    if (BEAT)
      cstore((u64*)(aux + ((size_t)((t & 31) * 256 + b_g) << 10) + (ht << 4) + (dgrp << 2)), tpk);
    else
      cstore((u64*)(aux + ((size_t)(b_g * 32 + t) << 10) + (ht << 4) + (dgrp << 2)), tpk);

    // ---------- arrive: syncthreads drains all threads' stores (vmcnt 0), then signal ----------
    __syncthreads();
    if (tid == 0) {
      const unsigned old = __hip_atomic_fetch_add(arr, 1u, __ATOMIC_RELAXED, SCOPE_AGENT);
      if (old == (unsigned)((t + 1) * 64 - 1))
        __hip_atomic_store(flg, (unsigned)(t + 1), __ATOMIC_RELAXED, SCOPE_AGENT);
    }
  }

  // ---------- tail: final output-projection window [T-16, T-1] ----------
  if (BEAT) {
    if (tid == 0) {
      while (__hip_atomic_load(flg, __ATOMIC_RELAXED, SCOPE_AGENT) < (unsigned)T)
        __builtin_amdgcn_s_sleep(2);
    }
    __syncthreads();
    __atomic_signal_fence(__ATOMIC_SEQ_CST);
    if (ht < 16)
      oproj_step(aux, linW, linb, dout, bt, T - 16 + ht, wave, quad, l15);
  }
}

// ================= launcher =================
extern "C" void kernel_launch(void* const* d_in, const int* in_sizes, int n_in,
                              void* d_out, int out_size, void* d_ws, size_t ws_size,
                              hipStream_t stream) {
  (void)in_sizes; (void)n_in; (void)out_size; (void)ws_size;
  const float* latent = (const float*)d_in[0];
  const float* inputs = (const float*)d_in[1];
  const float* mWih   = (const float*)d_in[2];
  const float* mWhh   = (const float*)d_in[3];
  const float* mb     = (const float*)d_in[4];
  const float* bWih   = (const float*)d_in[5];
  const float* bWhh   = (const float*)d_in[6];
  const float* bb     = (const float*)d_in[7];
  const float* linW   = (const float*)d_in[8];
  const float* linb   = (const float*)d_in[9];
  char* ws = (char*)d_ws;

  float* xg    = (float*)(ws + OFF_XG);
  u16* latb    = (u16*)(ws + OFF_LATB);
  u16* inpb    = (u16*)(ws + OFF_INPB);
  u16* mwihb   = (u16*)(ws + OFF_MWIH);
  u16* mwhhb   = (u16*)(ws + OFF_MWHH);
  u16* bwab    = (u16*)(ws + OFF_BWA);
  u16* bwbb    = (u16*)(ws + OFF_BWB);
  u16* bwhhb   = (u16*)(ws + OFF_BWHH);
  u16* linwb   = (u16*)(ws + OFF_LINW);
  u16* latT    = (u16*)(ws + OFF_LAT);
  u16* hm      = (u16*)(ws + OFF_HM);
  u16* hb      = (u16*)(ws + OFF_HB);
  u16* ring    = (u16*)(ws + OFF_RING);
  unsigned* cs = (unsigned*)(ws + OFF_CTR);

  constexpr unsigned SMEM = 64 * 1032 * 2 + 2 * 2112 * 4;  // 148,992 B
  hipFuncSetAttribute((const void*)(&lstm_rec<false>),
                      hipFuncAttributeMaxDynamicSharedMemorySize, (int)SMEM);
  hipFuncSetAttribute((const void*)(&lstm_rec<true>),
                      hipFuncAttributeMaxDynamicSharedMemorySize, (int)SMEM);

  // 1) prep: casts + splits + zero state/counters
  {
    const size_t total = 37356032ull;
    const int blocks = (int)((total + 255) / 256);
    prep_kernel<<<blocks, 256, 0, stream>>>(ws, latent, inputs, mWih, mWhh, bWih, bWhh, linW);
  }
  // 2) measure input projection: xg = latent @ mWih^T + mb   [8192x4096], K=512
  gemm_bt_bias<<<2048, 256, 0, stream>>>(latb, mwihb, mb, xg, 512, 4096);

  // 3) measure LSTM (T=32), writes lat = tanh(h)
  {
    const u16* a_whh = mwhhb; const float* a_xg = xg; const u16* a_wib = bwbb;
    const u16* a_inp = inpb;  const u16* a_lw = linwb; const float* a_lb = linb;
    u16* a_h0 = hm; u16* a_h1 = hm + Bz * Hz; u16* a_aux = latT;
    float* a_do = (float*)d_out; unsigned* a_ct = cs;
    void* margs[] = {&a_whh, &a_xg, &a_wib, &a_inp, &a_lw, &a_lb,
                     &a_h0, &a_h1, &a_aux, &a_do, &a_ct};
    hipError_t e = hipLaunchCooperativeKernel((const void*)(&lstm_rec<false>),
                                              dim3(256), dim3(256), margs, SMEM, stream);
    if (e != hipSuccess) {
      // fallback: plain launch (1 block/CU via 149KB LDS -> co-resident)
      lstm_rec<false><<<256, 256, SMEM, stream>>>(mwhhb, xg, bwbb, inpb, linwb, linb,
                                                  hm, hm + Bz * Hz, latT,
                                                  (float*)d_out, cs);
    }
  }
  // 4) beat lat projection: xg = lat @ bWih[:, :1024]^T + bb   [8192x4096], K=1024
  gemm_bt_bias<<<2048, 256, 0, stream>>>(latT, bwab, bb, xg, 1024, 4096);

  // 5) beat LSTM (T=512) with fused input-projection + fused output linear
  {
    const u16* a_whh = bwhhb; const float* a_xg = xg; const u16* a_wib = bwbb;
    const u16* a_inp = inpb;  const u16* a_lw = linwb; const float* a_lb = linb;
    u16* a_h0 = hb; u16* a_h1 = hb + Bz * Hz; u16* a_aux = ring;
    float* a_do = (float*)d_out; unsigned* a_ct = cs + 256;
    void* bargs[] = {&a_whh, &a_xg, &a_wib, &a_inp, &a_lw, &a_lb,
                     &a_h0, &a_h1, &a_aux, &a_do, &a_ct};
    hipError_t e = hipLaunchCooperativeKernel((const void*)(&lstm_rec<true>),
                                              dim3(256), dim3(256), bargs, SMEM, stream);
    if (e != hipSuccess) {
      lstm_rec<true><<<256, 256, SMEM, stream>>>(bwhhb, xg, bwbb, inpb, linwb, linb,
                                                 hb, hb + Bz * Hz, ring,
                                                 (float*)d_out, cs + 256);
    }
  }
}

// Round 3
// 13160.001 us; speedup vs baseline: 1.6508x; 1.0514x over previous
//
#include <hip/hip_runtime.h>
#include <stdint.h>

typedef short s16x8 __attribute__((ext_vector_type(8)));
typedef float f32x4 __attribute__((ext_vector_type(4)));
typedef unsigned short u16;
typedef unsigned long long u64;

#define DEV static __device__ __forceinline__
#define SCOPE_AGENT __HIP_MEMORY_SCOPE_AGENT

DEV u16 f2bf(float f) {
  unsigned u = __float_as_uint(f);
  u = (u + 0x7FFFu + ((u >> 16) & 1u)) >> 16;   // RNE
  return (u16)u;
}
DEV float sigf(float x) { return 1.0f / (1.0f + __expf(-x)); }
DEV float tanh_(float x) { float e = __expf(2.0f * x); return 1.0f - 2.0f / (e + 1.0f); }
DEV f32x4 MFMA(s16x8 a, s16x8 b, f32x4 c) {
  return __builtin_amdgcn_mfma_f32_16x16x32_bf16(a, b, c, 0, 0, 0);
}
// producer side: cache-bypassing store (sc0 sc1) -> visible at LLC without L2 flush
DEV void cstore(u64* p, u64 v) {
  __hip_atomic_store(p, v, __ATOMIC_RELAXED, SCOPE_AGENT);
}

// ---------------- problem dims ----------------
constexpr int Bz = 256, INz = 512, Hz = 1024, Oz = 128;
constexpr int G4 = 4096;     // 4*H
constexpr int TB = 512;      // beat timesteps (M*S)
constexpr int BM = 8192;     // B*M rows

// ---------------- workspace layout (bytes) ----------------
constexpr size_t OFF_XG   = 0;                                   // f32 [8192][4096]
constexpr size_t OFF_LATB = OFF_XG   + (size_t)BM * G4 * 4;      // bf16 [8192][512]
constexpr size_t OFF_INPB = OFF_LATB + (size_t)BM * INz * 2;     // bf16 [256*512][128]
constexpr size_t OFF_MWIH = OFF_INPB + (size_t)Bz * TB * Oz * 2; // bf16 [4096][512]
constexpr size_t OFF_MWHH = OFF_MWIH + (size_t)G4 * INz * 2;     // bf16 [4096][1024]
constexpr size_t OFF_BWA  = OFF_MWHH + (size_t)G4 * Hz * 2;      // bf16 [4096][1024]
constexpr size_t OFF_BWB  = OFF_BWA  + (size_t)G4 * Hz * 2;      // bf16 [4096][128]
constexpr size_t OFF_BWHH = OFF_BWB  + (size_t)G4 * Oz * 2;      // bf16 [4096][1024]
constexpr size_t OFF_LINW = OFF_BWHH + (size_t)G4 * Hz * 2;      // bf16 [128][1024]
constexpr size_t OFF_LAT  = OFF_LINW + (size_t)Oz * Hz * 2;      // bf16 [8192][1024]
constexpr size_t OFF_HM   = OFF_LAT  + (size_t)BM * Hz * 2;      // bf16 2x[256][1024]
constexpr size_t OFF_HB   = OFF_HM   + (size_t)2 * Bz * Hz * 2;  // bf16 2x[256][1024]
constexpr size_t OFF_RING = OFF_HB   + (size_t)2 * Bz * Hz * 2;  // bf16 [32][256][1024]
constexpr size_t OFF_CTR  = OFF_RING + (size_t)32 * Bz * Hz * 2; // counters (512 u32 = 2KB)

// ================= prep: casts / splits / zeroing =================
__global__ __launch_bounds__(256) void prep_kernel(
    char* __restrict__ ws, const float* __restrict__ latent,
    const float* __restrict__ inputs, const float* __restrict__ mWih,
    const float* __restrict__ mWhh, const float* __restrict__ bWih,
    const float* __restrict__ bWhh, const float* __restrict__ linW)
{
  size_t i = (size_t)blockIdx.x * 256 + threadIdx.x;
  const size_t n0 = (size_t)BM * INz;
  const size_t n1 = (size_t)Bz * TB * Oz;
  const size_t n2 = (size_t)G4 * INz;
  const size_t n3 = (size_t)G4 * Hz;
  const size_t n4 = (size_t)G4 * (Hz + Oz);
  const size_t n5 = (size_t)G4 * Hz;
  const size_t n6 = (size_t)Oz * Hz;
  const size_t n7 = (size_t)2 * Bz * Hz;
  const size_t n8 = (size_t)2 * Bz * Hz;
  const size_t n9 = 512;
  if (i < n0) { ((u16*)(ws + OFF_LATB))[i] = f2bf(latent[i]); return; } i -= n0;
  if (i < n1) { ((u16*)(ws + OFF_INPB))[i] = f2bf(inputs[i]); return; } i -= n1;
  if (i < n2) { ((u16*)(ws + OFF_MWIH))[i] = f2bf(mWih[i]);   return; } i -= n2;
  if (i < n3) { ((u16*)(ws + OFF_MWHH))[i] = f2bf(mWhh[i]);   return; } i -= n3;
  if (i < n4) {
    size_t r = i / 1152, c = i - r * 1152;
    float v = bWih[i];
    if (c < 1024) ((u16*)(ws + OFF_BWA))[r * 1024 + c] = f2bf(v);
    else          ((u16*)(ws + OFF_BWB))[r * 128 + (c - 1024)] = f2bf(v);
    return;
  } i -= n4;
  if (i < n5) { ((u16*)(ws + OFF_BWHH))[i] = f2bf(bWhh[i]);   return; } i -= n5;
  if (i < n6) { ((u16*)(ws + OFF_LINW))[i] = f2bf(linW[i]);   return; } i -= n6;
  if (i < n7) { ((u16*)(ws + OFF_HM))[i] = 0; return; } i -= n7;
  if (i < n8) { ((u16*)(ws + OFF_HB))[i] = 0; return; } i -= n8;
  if (i < n9) { ((unsigned*)(ws + OFF_CTR))[i] = 0; return; }
}

// ================= projection GEMM: C[M][N](f32) = A[M][K](bf16) @ B[N][K]^T + bias =================
__global__ __launch_bounds__(256) void gemm_bt_bias(
    const u16* __restrict__ A, const u16* __restrict__ Bw,
    const float* __restrict__ bias, float* __restrict__ C, int K, int Ndim)
{
  __shared__ u16 As[128 * 40];
  __shared__ u16 Bs[128 * 40];
  const int bx = blockIdx.x & 63;
  const int by = blockIdx.x >> 6;
  const int m0 = bx * 128, n0 = by * 128;
  const int tid = threadIdx.x, lane = tid & 63, wave = tid >> 6;
  const int quad = lane >> 4, l15 = lane & 15;
  const int wm = wave & 1, wn = wave >> 1;
  const int srow = tid >> 1, shalf = tid & 1;

  f32x4 acc[4][4];
  #pragma unroll
  for (int mi = 0; mi < 4; ++mi)
    #pragma unroll
    for (int ni = 0; ni < 4; ++ni) { f32x4 z = {0.f,0.f,0.f,0.f}; acc[mi][ni] = z; }

  const int KC = K >> 5;
  for (int kc = 0; kc < KC; ++kc) {
    const size_t ka = (size_t)(m0 + srow) * K + kc * 32 + shalf * 16;
    s16x8 va0 = *(const s16x8*)(A + ka);
    s16x8 va1 = *(const s16x8*)(A + ka + 8);
    const size_t kb = (size_t)(n0 + srow) * K + kc * 32 + shalf * 16;
    s16x8 vb0 = *(const s16x8*)(Bw + kb);
    s16x8 vb1 = *(const s16x8*)(Bw + kb + 8);
    __syncthreads();
    *(s16x8*)(As + srow * 40 + shalf * 16)     = va0;
    *(s16x8*)(As + srow * 40 + shalf * 16 + 8) = va1;
    *(s16x8*)(Bs + srow * 40 + shalf * 16)     = vb0;
    *(s16x8*)(Bs + srow * 40 + shalf * 16 + 8) = vb1;
    __syncthreads();
    s16x8 af[4], bf[4];
    #pragma unroll
    for (int mi = 0; mi < 4; ++mi)
      af[mi] = *(const s16x8*)(As + (wm * 64 + mi * 16 + l15) * 40 + quad * 8);
    #pragma unroll
    for (int ni = 0; ni < 4; ++ni)
      bf[ni] = *(const s16x8*)(Bs + (wn * 64 + ni * 16 + l15) * 40 + quad * 8);
    #pragma unroll
    for (int mi = 0; mi < 4; ++mi)
      #pragma unroll
      for (int ni = 0; ni < 4; ++ni)
        acc[mi][ni] = MFMA(af[mi], bf[ni], acc[mi][ni]);
  }
  #pragma unroll
  for (int mi = 0; mi < 4; ++mi)
    #pragma unroll
    for (int ni = 0; ni < 4; ++ni) {
      const int col = n0 + wn * 64 + ni * 16 + l15;
      const float bs = bias[col];
      #pragma unroll
      for (int r = 0; r < 4; ++r) {
        const int row = m0 + wm * 64 + mi * 16 + quad * 4 + r;
        C[(size_t)row * Ndim + col] = acc[mi][ni][r] + bs;
      }
    }
}

// ---- duty output projection for one timestep t0 (64 batches x 128 out, K=1024) ----
// called strictly after the per-step acquire (buffer_inv) -> plain cached loads OK
DEV void oproj_step(const u16* __restrict__ aux, const u16* __restrict__ linW,
                    const float* __restrict__ linb, float* __restrict__ dout,
                    int bt, int t0, int wave, int quad, int l15)
{
  const u16* Ar = aux + (((size_t)((t0 & 31) * 256 + (bt << 6))) << 10);
  const u16* orp = Ar + (((size_t)(wave << 4) + l15) << 10) + (quad << 3);
  const u16* lp[8];
  #pragma unroll
  for (int nt = 0; nt < 8; ++nt)
    lp[nt] = linW + (((size_t)(nt << 4) + l15) << 10) + (quad << 3);
  f32x4 oacc[8];
  #pragma unroll
  for (int nt = 0; nt < 8; ++nt) { f32x4 z = {0.f,0.f,0.f,0.f}; oacc[nt] = z; }
  s16x8 opf[4];
  #pragma unroll
  for (int g = 0; g < 4; ++g)
    opf[g] = *(const s16x8*)(orp + (g << 5));
  #pragma unroll
  for (int kc = 0; kc < 32; ++kc) {
    const s16x8 a = opf[kc & 3];
    #pragma unroll
    for (int nt = 0; nt < 8; ++nt) {
      s16x8 b = *(const s16x8*)(lp[nt] + (kc << 5));
      oacc[nt] = MFMA(a, b, oacc[nt]);
    }
    if (kc < 28)
      opf[kc & 3] = *(const s16x8*)(orp + ((kc + 4) << 5));
  }
  #pragma unroll
  for (int nt = 0; nt < 8; ++nt) {
    const int col = (nt << 4) + l15;
    const float bs = linb[col];
    #pragma unroll
    for (int r = 0; r < 4; ++r) {
      const int bg2 = (bt << 6) + (wave << 4) + (quad << 2) + r;
      dout[((size_t)bg2 * 512 + t0) * 128 + col] = oacc[nt][r] + bs;
    }
  }
}

// ================= persistent recurrent LSTM =================
// R6 == R5 resubmission (round-2 bench was an infra failure, no kernel verdict).
//  - h / ring CONSUMER path: PLAIN cached s16x8 loads. Coherence: producers
//    write-through to LLC (cstore sc0 sc1); after the flag-spin, tid0 does ONE
//    agent-scope ACQUIRE load -> s_waitcnt + buffer_inv (invalidates CU L1 +
//    XCD L2), then __syncthreads orders the whole block after it. First touch
//    refills from LLC; ~8 blocks/XCD share the same 128KB h tile via L2 ->
//    ~8x fewer LLC transactions, 2x fewer load instrs.
//  - t=0 reads covered by dispatch-start cache invalidate + stream ordering.
template<bool BEAT>
__global__ __launch_bounds__(256, 1) void lstm_rec(
    const u16* __restrict__ Whh,   // [4096][1024] bf16
    const float* __restrict__ xg,  // [8192][4096] f32 rows = b*32 + m
    const u16* __restrict__ WihB,  // [4096][128]  (beat)
    const u16* __restrict__ inp,   // [256*512][128] (beat)
    const u16* __restrict__ linW,  // [128][1024]  (beat)
    const float* __restrict__ linb,// [128]        (beat)
    u16* __restrict__ hbuf0, u16* __restrict__ hbuf1,
    u16* __restrict__ aux,         // measure: lat [8192][1024]; beat: ring [32][256][1024]
    float* __restrict__ dout,      // beat: [256][512][128]
    unsigned* __restrict__ ctr)
{
  extern __shared__ char smem[];
  u16* sW = (u16*)smem;                         // 64 rows x (1024+8)
  float* sEx = (float*)(smem + 64 * 1032 * 2);  // 2 bufs x 64 x 33 floats

  const int blk = blockIdx.x;
  const int bt = blk >> 6, ht = blk & 63;
  const int tid = threadIdx.x;
  const int wave = tid >> 6, lane = tid & 63;
  const int quad = lane >> 4, l15 = lane & 15;
  const int kh = wave & 1, nh = wave >> 1;

  // per-batch-tile barrier: arrive counter and go flag, 128B apart; groups 256B apart
  unsigned* const arr = ctr + (bt << 6);
  unsigned* const flg = arr + 32;

  // stage Whh slice (rows {g*1024 + ht*16 + d}) into LDS, once
  for (int c = tid; c < 8192; c += 256) {
    const int rr = c >> 7;
    const int cc = (c & 127) << 3;
    const int gr = ((rr >> 4) << 10) + (ht << 4) + (rr & 15);
    *(s16x8*)(sW + rr * 1032 + cc) = *(const s16x8*)(Whh + ((size_t)gr << 10) + cc);
  }
  __syncthreads();

  const int batch_l = tid & 63, dgrp = tid >> 6;
  const int b_g = (bt << 6) + batch_l;
  float cst[4] = {0.f, 0.f, 0.f, 0.f};
  float xgv[4][4];

  const int T = BEAT ? 512 : 32;
  const u16* hbufs[2] = {hbuf0, hbuf1};

  for (int t = 0; t < T; ++t) {
    const u16* hp = hbufs[t & 1];
    u16* hn = const_cast<u16*>(hbufs[(t + 1) & 1]);

    // ---------- overlap zone: barrier-independent work ----------
    if (!BEAT || (t & 15) == 0) {   // lat-projection slice (incl. bias), fp32
      const int mrow = BEAT ? (t >> 4) : t;
      const float* xr = xg + (size_t)(b_g * 32 + mrow) * 4096 + (ht << 4) + (dgrp << 2);
      #pragma unroll
      for (int g = 0; g < 4; ++g)
        #pragma unroll
        for (int j = 0; j < 4; ++j) xgv[g][j] = xr[g * 1024 + j];
    }

    f32x4 acc[4][2];
    #pragma unroll
    for (int mi = 0; mi < 4; ++mi)
      #pragma unroll
      for (int gi = 0; gi < 2; ++gi) { f32x4 z = {0.f,0.f,0.f,0.f}; acc[mi][gi] = z; }

    if (BEAT) {  // beat-input projection: inp[:,t,:] @ WihB^T (K=128), h-independent
      #pragma unroll
      for (int kc = 0; kc < 2; ++kc) {
        const int k = (kh << 6) + (kc << 5) + (quad << 3);
        s16x8 bfr0 = *(const s16x8*)(WihB + (size_t)(((nh * 2 + 0) << 10) + (ht << 4) + l15) * 128 + k);
        s16x8 bfr1 = *(const s16x8*)(WihB + (size_t)(((nh * 2 + 1) << 10) + (ht << 4) + l15) * 128 + k);
        #pragma unroll
        for (int mi = 0; mi < 4; ++mi) {
          s16x8 afr = *(const s16x8*)(inp + ((size_t)((bt << 6) + (mi << 4) + l15) * 512 + t) * 128 + k);
          acc[mi][0] = MFMA(afr, bfr0, acc[mi][0]);
          acc[mi][1] = MFMA(afr, bfr1, acc[mi][1]);
        }
      }
    }

    // ---------- wait: all 64 blocks of this bt finished step t-1 ----------
    if (t) {
      if (tid == 0) {
        while (__hip_atomic_load(flg, __ATOMIC_RELAXED, SCOPE_AGENT) < (unsigned)t)
          __builtin_amdgcn_s_sleep(2);
        // ONE acquire per block per step: s_waitcnt + buffer_inv (L1+L2) so
        // plain cached loads below observe this step's LLC-resident h/ring.
        (void)__hip_atomic_load(flg, __ATOMIC_ACQUIRE, SCOPE_AGENT);
      }
      __syncthreads();
      __atomic_signal_fence(__ATOMIC_SEQ_CST);
    }

    // ---------- duty fused output projection, window [t-16, t-1] ----------
    if (BEAT && t && (t & 15) == 0 && ht < 16)
      oproj_step(aux, linW, linb, dout, bt, t - 16 + ht, wave, quad, l15);

    // ---------- recurrent GEMM: h(t-1) @ Whh^T, depth-4 pipelined, cached loads ----------
    {
      const u16* hbase = hp + ((size_t)(bt << 6) << 10);
      const u16* rp[4];
      #pragma unroll
      for (int mi = 0; mi < 4; ++mi)
        rp[mi] = hbase + (((size_t)(mi << 4) + l15) << 10) + (kh << 9) + (quad << 3);

      s16x8 pf[4][4];
      #pragma unroll
      for (int g = 0; g < 4; ++g)
        #pragma unroll
        for (int mi = 0; mi < 4; ++mi)
          pf[g][mi] = *(const s16x8*)(rp[mi] + (g << 5));

      const u16* sB0 = sW + (((nh * 2 + 0) << 4) + l15) * 1032 + (kh << 9) + (quad << 3);
      const u16* sB1 = sW + (((nh * 2 + 1) << 4) + l15) * 1032 + (kh << 9) + (quad << 3);
      #pragma unroll
      for (int kc = 0; kc < 16; ++kc) {
        s16x8 bfr0 = *(const s16x8*)(sB0 + (kc << 5));
        s16x8 bfr1 = *(const s16x8*)(sB1 + (kc << 5));
        #pragma unroll
        for (int mi = 0; mi < 4; ++mi) {
          acc[mi][0] = MFMA(pf[kc & 3][mi], bfr0, acc[mi][0]);
          acc[mi][1] = MFMA(pf[kc & 3][mi], bfr1, acc[mi][1]);
        }
        if (kc < 12) {
          #pragma unroll
          for (int mi = 0; mi < 4; ++mi)
            pf[kc & 3][mi] = *(const s16x8*)(rp[mi] + ((kc + 4) << 5));
        }
      }
    }

    // ---------- merge k-halves via LDS ----------
    if (kh == 1) {
      #pragma unroll
      for (int mi = 0; mi < 4; ++mi)
        #pragma unroll
        for (int gi = 0; gi < 2; ++gi)
          #pragma unroll
          for (int r = 0; r < 4; ++r)
            sEx[nh * 2112 + ((mi << 4) + (quad << 2) + r) * 33 + (gi << 4) + l15] = acc[mi][gi][r];
    }
    __syncthreads();
    if (kh == 0) {
      #pragma unroll
      for (int mi = 0; mi < 4; ++mi)
        #pragma unroll
        for (int gi = 0; gi < 2; ++gi)
          #pragma unroll
          for (int r = 0; r < 4; ++r) {
            const int idx = nh * 2112 + ((mi << 4) + (quad << 2) + r) * 33 + (gi << 4) + l15;
            sEx[idx] += acc[mi][gi][r];
          }
    }
    __syncthreads();

    // ---------- element-wise LSTM cell update (thread owns 4 dims of 1 batch) ----------
    float hv[4], tv[4];
    {
      const int bo = batch_l * 33;
      #pragma unroll
      for (int j = 0; j < 4; ++j) {
        const int d = (dgrp << 2) + j;
        const float pi = sEx[bo + d]              + xgv[0][j];
        const float pf_ = sEx[bo + 16 + d]        + xgv[1][j];
        const float pg = sEx[2112 + bo + d]       + xgv[2][j];
        const float po = sEx[2112 + bo + 16 + d]  + xgv[3][j];
        const float iv = sigf(pi), fv = sigf(pf_), gv = tanh_(pg), ov = sigf(po);
        cst[j] = fv * cst[j] + iv * gv;
        hv[j] = ov * tanh_(cst[j]);
        tv[j] = tanh_(hv[j]);
      }
    }
    u64 hpk = (u64)f2bf(hv[0]) | ((u64)f2bf(hv[1]) << 16)
            | ((u64)f2bf(hv[2]) << 32) | ((u64)f2bf(hv[3]) << 48);
    u64 tpk = (u64)f2bf(tv[0]) | ((u64)f2bf(tv[1]) << 16)
            | ((u64)f2bf(tv[2]) << 32) | ((u64)f2bf(tv[3]) << 48);
    cstore((u64*)(hn + ((size_t)b_g << 10) + (ht << 4) + (dgrp << 2)), hpk);
    if (BEAT)
      cstore((u64*)(aux + ((size_t)((t & 31) * 256 + b_g) << 10) + (ht << 4) + (dgrp << 2)), tpk);
    else
      cstore((u64*)(aux + ((size_t)(b_g * 32 + t) << 10) + (ht << 4) + (dgrp << 2)), tpk);

    // ---------- arrive: syncthreads drains all threads' stores, then signal ----------
    __syncthreads();
    if (tid == 0) {
      const unsigned old = __hip_atomic_fetch_add(arr, 1u, __ATOMIC_RELAXED, SCOPE_AGENT);
      if (old == (unsigned)((t + 1) * 64 - 1))
        __hip_atomic_store(flg, (unsigned)(t + 1), __ATOMIC_RELAXED, SCOPE_AGENT);
    }
  }

  // ---------- tail: final output-projection window [T-16, T-1] ----------
  if (BEAT) {
    if (tid == 0) {
      while (__hip_atomic_load(flg, __ATOMIC_RELAXED, SCOPE_AGENT) < (unsigned)T)
        __builtin_amdgcn_s_sleep(2);
      (void)__hip_atomic_load(flg, __ATOMIC_ACQUIRE, SCOPE_AGENT);
    }
    __syncthreads();
    __atomic_signal_fence(__ATOMIC_SEQ_CST);
    if (ht < 16)
      oproj_step(aux, linW, linb, dout, bt, T - 16 + ht, wave, quad, l15);
  }
}

// ================= launcher =================
extern "C" void kernel_launch(void* const* d_in, const int* in_sizes, int n_in,
                              void* d_out, int out_size, void* d_ws, size_t ws_size,
                              hipStream_t stream) {
  (void)in_sizes; (void)n_in; (void)out_size; (void)ws_size;
  const float* latent = (const float*)d_in[0];
  const float* inputs = (const float*)d_in[1];
  const float* mWih   = (const float*)d_in[2];
  const float* mWhh   = (const float*)d_in[3];
  const float* mb     = (const float*)d_in[4];
  const float* bWih   = (const float*)d_in[5];
  const float* bWhh   = (const float*)d_in[6];
  const float* bb     = (const float*)d_in[7];
  const float* linW   = (const float*)d_in[8];
  const float* linb   = (const float*)d_in[9];
  char* ws = (char*)d_ws;

  float* xg    = (float*)(ws + OFF_XG);
  u16* latb    = (u16*)(ws + OFF_LATB);
  u16* inpb    = (u16*)(ws + OFF_INPB);
  u16* mwihb   = (u16*)(ws + OFF_MWIH);
  u16* mwhhb   = (u16*)(ws + OFF_MWHH);
  u16* bwab    = (u16*)(ws + OFF_BWA);
  u16* bwbb    = (u16*)(ws + OFF_BWB);
  u16* bwhhb   = (u16*)(ws + OFF_BWHH);
  u16* linwb   = (u16*)(ws + OFF_LINW);
  u16* latT    = (u16*)(ws + OFF_LAT);
  u16* hm      = (u16*)(ws + OFF_HM);
  u16* hb      = (u16*)(ws + OFF_HB);
  u16* ring    = (u16*)(ws + OFF_RING);
  unsigned* cs = (unsigned*)(ws + OFF_CTR);

  constexpr unsigned SMEM = 64 * 1032 * 2 + 2 * 2112 * 4;  // 148,992 B
  hipFuncSetAttribute((const void*)(&lstm_rec<false>),
                      hipFuncAttributeMaxDynamicSharedMemorySize, (int)SMEM);
  hipFuncSetAttribute((const void*)(&lstm_rec<true>),
                      hipFuncAttributeMaxDynamicSharedMemorySize, (int)SMEM);

  // 1) prep: casts + splits + zero state/counters
  {
    const size_t total = 37356032ull;
    const int blocks = (int)((total + 255) / 256);
    prep_kernel<<<blocks, 256, 0, stream>>>(ws, latent, inputs, mWih, mWhh, bWih, bWhh, linW);
  }
  // 2) measure input projection: xg = latent @ mWih^T + mb   [8192x4096], K=512
  gemm_bt_bias<<<2048, 256, 0, stream>>>(latb, mwihb, mb, xg, 512, 4096);

  // 3) measure LSTM (T=32), writes lat = tanh(h)
  {
    const u16* a_whh = mwhhb; const float* a_xg = xg; const u16* a_wib = bwbb;
    const u16* a_inp = inpb;  const u16* a_lw = linwb; const float* a_lb = linb;
    u16* a_h0 = hm; u16* a_h1 = hm + Bz * Hz; u16* a_aux = latT;
    float* a_do = (float*)d_out; unsigned* a_ct = cs;
    void* margs[] = {&a_whh, &a_xg, &a_wib, &a_inp, &a_lw, &a_lb,
                     &a_h0, &a_h1, &a_aux, &a_do, &a_ct};
    hipError_t e = hipLaunchCooperativeKernel((const void*)(&lstm_rec<false>),
                                              dim3(256), dim3(256), margs, SMEM, stream);
    if (e != hipSuccess) {
      // fallback: plain launch (1 block/CU via 149KB LDS -> co-resident)
      lstm_rec<false><<<256, 256, SMEM, stream>>>(mwhhb, xg, bwbb, inpb, linwb, linb,
                                                  hm, hm + Bz * Hz, latT,
                                                  (float*)d_out, cs);
    }
  }
  // 4) beat lat projection: xg = lat @ bWih[:, :1024]^T + bb   [8192x4096], K=1024
  gemm_bt_bias<<<2048, 256, 0, stream>>>(latT, bwab, bb, xg, 1024, 4096);

  // 5) beat LSTM (T=512) with fused input-projection + fused output linear
  {
    const u16* a_whh = bwhhb; const float* a_xg = xg; const u16* a_wib = bwbb;
    const u16* a_inp = inpb;  const u16* a_lw = linwb; const float* a_lb = linb;
    u16* a_h0 = hb; u16* a_h1 = hb + Bz * Hz; u16* a_aux = ring;
    float* a_do = (float*)d_out; unsigned* a_ct = cs + 256;
    void* bargs[] = {&a_whh, &a_xg, &a_wib, &a_inp, &a_lw, &a_lb,
                     &a_h0, &a_h1, &a_aux, &a_do, &a_ct};
    hipError_t e = hipLaunchCooperativeKernel((const void*)(&lstm_rec<true>),
                                              dim3(256), dim3(256), bargs, SMEM, stream);
    if (e != hipSuccess) {
      lstm_rec<true><<<256, 256, SMEM, stream>>>(bwhhb, xg, bwbb, inpb, linwb, linb,
                                                 hb, hb + Bz * Hz, ring,
                                                 (float*)d_out, cs + 256);
    }
  }
}

// Round 4
// 12512.614 us; speedup vs baseline: 1.7362x; 1.0517x over previous
//
#include <hip/hip_runtime.h>
#include <stdint.h>

typedef short s16x8 __attribute__((ext_vector_type(8)));
typedef float f32x4 __attribute__((ext_vector_type(4)));
typedef unsigned short u16;
typedef unsigned int u32;
typedef unsigned long long u64;

#define DEV static __device__ __forceinline__
#define SCOPE_AGENT __HIP_MEMORY_SCOPE_AGENT

DEV u16 f2bf(float f) {
  unsigned u = __float_as_uint(f);
  u = (u + 0x7FFFu + ((u >> 16) & 1u)) >> 16;   // RNE
  return (u16)u;
}
DEV float sigf(float x) { return 1.0f / (1.0f + __expf(-x)); }
DEV float tanh_(float x) { float e = __expf(2.0f * x); return 1.0f - 2.0f / (e + 1.0f); }
DEV f32x4 MFMA(s16x8 a, s16x8 b, f32x4 c) {
  return __builtin_amdgcn_mfma_f32_16x16x32_bf16(a, b, c, 0, 0, 0);
}
// producer side: cache-bypassing store -> visible at LLC without L2 flush
DEV void cstore32(u32* p, u32 v) {
  __hip_atomic_store(p, v, __ATOMIC_RELAXED, SCOPE_AGENT);
}

// ---------------- problem dims ----------------
constexpr int Bz = 256, INz = 512, Hz = 1024, Oz = 128;
constexpr int G4 = 4096;     // 4*H
constexpr int TB = 512;      // beat timesteps (M*S)
constexpr int BM = 8192;     // B*M rows

// ---------------- workspace layout (bytes) ----------------
constexpr size_t OFF_XG   = 0;                                   // f32 [8192][4096]
constexpr size_t OFF_LATB = OFF_XG   + (size_t)BM * G4 * 4;      // bf16 [8192][512]
constexpr size_t OFF_INPB = OFF_LATB + (size_t)BM * INz * 2;     // bf16 [256*512][128]
constexpr size_t OFF_MWIH = OFF_INPB + (size_t)Bz * TB * Oz * 2; // bf16 [4096][512]
constexpr size_t OFF_MWHH = OFF_MWIH + (size_t)G4 * INz * 2;     // bf16 [4096][1024]
constexpr size_t OFF_BWA  = OFF_MWHH + (size_t)G4 * Hz * 2;      // bf16 [4096][1024]
constexpr size_t OFF_BWB  = OFF_BWA  + (size_t)G4 * Hz * 2;      // bf16 [4096][128]
constexpr size_t OFF_BWHH = OFF_BWB  + (size_t)G4 * Oz * 2;      // bf16 [4096][1024]
constexpr size_t OFF_LINW = OFF_BWHH + (size_t)G4 * Hz * 2;      // bf16 [128][1024]
constexpr size_t OFF_LAT  = OFF_LINW + (size_t)Oz * Hz * 2;      // bf16 [8192][1024]
constexpr size_t OFF_HM   = OFF_LAT  + (size_t)BM * Hz * 2;      // bf16 2x[256][1024]
constexpr size_t OFF_HB   = OFF_HM   + (size_t)2 * Bz * Hz * 2;  // bf16 2x[256][1024]
constexpr size_t OFF_RING = OFF_HB   + (size_t)2 * Bz * Hz * 2;  // bf16 [32][256][1024]
constexpr size_t OFF_CTR  = OFF_RING + (size_t)32 * Bz * Hz * 2; // counters (512 u32 = 2KB)

// ================= prep: casts / splits / zeroing =================
__global__ __launch_bounds__(256) void prep_kernel(
    char* __restrict__ ws, const float* __restrict__ latent,
    const float* __restrict__ inputs, const float* __restrict__ mWih,
    const float* __restrict__ mWhh, const float* __restrict__ bWih,
    const float* __restrict__ bWhh, const float* __restrict__ linW)
{
  size_t i = (size_t)blockIdx.x * 256 + threadIdx.x;
  const size_t n0 = (size_t)BM * INz;
  const size_t n1 = (size_t)Bz * TB * Oz;
  const size_t n2 = (size_t)G4 * INz;
  const size_t n3 = (size_t)G4 * Hz;
  const size_t n4 = (size_t)G4 * (Hz + Oz);
  const size_t n5 = (size_t)G4 * Hz;
  const size_t n6 = (size_t)Oz * Hz;
  const size_t n7 = (size_t)2 * Bz * Hz;
  const size_t n8 = (size_t)2 * Bz * Hz;
  const size_t n9 = 512;
  if (i < n0) { ((u16*)(ws + OFF_LATB))[i] = f2bf(latent[i]); return; } i -= n0;
  if (i < n1) { ((u16*)(ws + OFF_INPB))[i] = f2bf(inputs[i]); return; } i -= n1;
  if (i < n2) { ((u16*)(ws + OFF_MWIH))[i] = f2bf(mWih[i]);   return; } i -= n2;
  if (i < n3) { ((u16*)(ws + OFF_MWHH))[i] = f2bf(mWhh[i]);   return; } i -= n3;
  if (i < n4) {
    size_t r = i / 1152, c = i - r * 1152;
    float v = bWih[i];
    if (c < 1024) ((u16*)(ws + OFF_BWA))[r * 1024 + c] = f2bf(v);
    else          ((u16*)(ws + OFF_BWB))[r * 128 + (c - 1024)] = f2bf(v);
    return;
  } i -= n4;
  if (i < n5) { ((u16*)(ws + OFF_BWHH))[i] = f2bf(bWhh[i]);   return; } i -= n5;
  if (i < n6) { ((u16*)(ws + OFF_LINW))[i] = f2bf(linW[i]);   return; } i -= n6;
  if (i < n7) { ((u16*)(ws + OFF_HM))[i] = 0; return; } i -= n7;
  if (i < n8) { ((u16*)(ws + OFF_HB))[i] = 0; return; } i -= n8;
  if (i < n9) { ((unsigned*)(ws + OFF_CTR))[i] = 0; return; }
}

// ================= projection GEMM: C[M][N](f32) = A[M][K](bf16) @ B[N][K]^T + bias =================
__global__ __launch_bounds__(256) void gemm_bt_bias(
    const u16* __restrict__ A, const u16* __restrict__ Bw,
    const float* __restrict__ bias, float* __restrict__ C, int K, int Ndim)
{
  __shared__ u16 As[128 * 40];
  __shared__ u16 Bs[128 * 40];
  const int bx = blockIdx.x & 63;
  const int by = blockIdx.x >> 6;
  const int m0 = bx * 128, n0 = by * 128;
  const int tid = threadIdx.x, lane = tid & 63, wave = tid >> 6;
  const int quad = lane >> 4, l15 = lane & 15;
  const int wm = wave & 1, wn = wave >> 1;
  const int srow = tid >> 1, shalf = tid & 1;

  f32x4 acc[4][4];
  #pragma unroll
  for (int mi = 0; mi < 4; ++mi)
    #pragma unroll
    for (int ni = 0; ni < 4; ++ni) { f32x4 z = {0.f,0.f,0.f,0.f}; acc[mi][ni] = z; }

  const int KC = K >> 5;
  for (int kc = 0; kc < KC; ++kc) {
    const size_t ka = (size_t)(m0 + srow) * K + kc * 32 + shalf * 16;
    s16x8 va0 = *(const s16x8*)(A + ka);
    s16x8 va1 = *(const s16x8*)(A + ka + 8);
    const size_t kb = (size_t)(n0 + srow) * K + kc * 32 + shalf * 16;
    s16x8 vb0 = *(const s16x8*)(Bw + kb);
    s16x8 vb1 = *(const s16x8*)(Bw + kb + 8);
    __syncthreads();
    *(s16x8*)(As + srow * 40 + shalf * 16)     = va0;
    *(s16x8*)(As + srow * 40 + shalf * 16 + 8) = va1;
    *(s16x8*)(Bs + srow * 40 + shalf * 16)     = vb0;
    *(s16x8*)(Bs + srow * 40 + shalf * 16 + 8) = vb1;
    __syncthreads();
    s16x8 af[4], bf[4];
    #pragma unroll
    for (int mi = 0; mi < 4; ++mi)
      af[mi] = *(const s16x8*)(As + (wm * 64 + mi * 16 + l15) * 40 + quad * 8);
    #pragma unroll
    for (int ni = 0; ni < 4; ++ni)
      bf[ni] = *(const s16x8*)(Bs + (wn * 64 + ni * 16 + l15) * 40 + quad * 8);
    #pragma unroll
    for (int mi = 0; mi < 4; ++mi)
      #pragma unroll
      for (int ni = 0; ni < 4; ++ni)
        acc[mi][ni] = MFMA(af[mi], bf[ni], acc[mi][ni]);
  }
  #pragma unroll
  for (int mi = 0; mi < 4; ++mi)
    #pragma unroll
    for (int ni = 0; ni < 4; ++ni) {
      const int col = n0 + wn * 64 + ni * 16 + l15;
      const float bs = bias[col];
      #pragma unroll
      for (int r = 0; r < 4; ++r) {
        const int row = m0 + wm * 64 + mi * 16 + quad * 4 + r;
        C[(size_t)row * Ndim + col] = acc[mi][ni][r] + bs;
      }
    }
}

// ---- duty output projection for one timestep t0 (64 batches x 128 out, K=1024) ----
// called strictly after the per-step acquire (buffer_inv) -> plain cached loads OK
DEV void oproj_step(const u16* __restrict__ aux, const u16* __restrict__ linW,
                    const float* __restrict__ linb, float* __restrict__ dout,
                    int bt, int t0, int wave, int quad, int l15)
{
  const u16* Ar = aux + (((size_t)((t0 & 31) * 256 + (bt << 6))) << 10);
  const u16* orp = Ar + (((size_t)(wave << 4) + l15) << 10) + (quad << 3);
  const u16* lp[8];
  #pragma unroll
  for (int nt = 0; nt < 8; ++nt)
    lp[nt] = linW + (((size_t)(nt << 4) + l15) << 10) + (quad << 3);
  f32x4 oacc[8];
  #pragma unroll
  for (int nt = 0; nt < 8; ++nt) { f32x4 z = {0.f,0.f,0.f,0.f}; oacc[nt] = z; }
  s16x8 opf[4];
  #pragma unroll
  for (int g = 0; g < 4; ++g)
    opf[g] = *(const s16x8*)(orp + (g << 5));
  #pragma unroll
  for (int kc = 0; kc < 32; ++kc) {
    const s16x8 a = opf[kc & 3];
    #pragma unroll
    for (int nt = 0; nt < 8; ++nt) {
      s16x8 b = *(const s16x8*)(lp[nt] + (kc << 5));
      oacc[nt] = MFMA(a, b, oacc[nt]);
    }
    if (kc < 28)
      opf[kc & 3] = *(const s16x8*)(orp + ((kc + 4) << 5));
  }
  #pragma unroll
  for (int nt = 0; nt < 8; ++nt) {
    const int col = (nt << 4) + l15;
    const float bs = linb[col];
    #pragma unroll
    for (int r = 0; r < 4; ++r) {
      const int bg2 = (bt << 6) + (wave << 4) + (quad << 2) + r;
      dout[((size_t)bg2 * 512 + t0) * 128 + col] = oacc[nt][r] + bs;
    }
  }
}

// ================= persistent recurrent LSTM =================
// R7: 2 blocks/CU for latency overlap.
//  - Block shrunk to 8 H-dims (sW = 32 rows x 1032 = 66KB; sEx = 64x33 f32 = 8.4KB;
//    total 74.5KB) + __launch_bounds__(256,2) (VGPR<=128) -> 2 blocks/CU, 8 waves/CU.
//    512 blocks = 4 groups x 128; independent groups drift -> co-resident block
//    computes while the other waits, hiding barrier/load latency.
//  - Wave decomposition: wave = batch-quarter (16 batches), FULL K=1024 per wave.
//    No k-half merge (1 syncthreads, no LDS adds), no duplicate h loads, acc = 8 VGPR,
//    a-frag pipeline depth 8.
//  - Sync protocol unchanged from R6 (flag spin + one agent-acquire/bufinv + arrive RMW).
template<bool BEAT>
__global__ __launch_bounds__(256, 2) void lstm_rec(
    const u16* __restrict__ Whh,   // [4096][1024] bf16
    const float* __restrict__ xg,  // [8192][4096] f32 rows = b*32 + m
    const u16* __restrict__ WihB,  // [4096][128]  (beat)
    const u16* __restrict__ inp,   // [256*512][128] (beat)
    const u16* __restrict__ linW,  // [128][1024]  (beat)
    const float* __restrict__ linb,// [128]        (beat)
    u16* __restrict__ hbuf0, u16* __restrict__ hbuf1,
    u16* __restrict__ aux,         // measure: lat [8192][1024]; beat: ring [32][256][1024]
    float* __restrict__ dout,      // beat: [256][512][128]
    unsigned* __restrict__ ctr)
{
  extern __shared__ char smem[];
  u16* sW = (u16*)smem;                         // 32 rows x (1024+8)
  float* sEx = (float*)(smem + 32 * 1032 * 2);  // 64 x 33 floats

  const int blk = blockIdx.x;
  const int bt = blk >> 7, ht = blk & 127;      // 4 groups x 128 blocks; 8 dims each
  const int tid = threadIdx.x;
  const int wave = tid >> 6, lane = tid & 63;
  const int quad = lane >> 4, l15 = lane & 15;

  // per-batch-tile barrier: arrive counter and go flag, 128B apart; groups 256B apart
  unsigned* const arr = ctr + (bt << 6);
  unsigned* const flg = arr + 32;

  // stage Whh slice (rows {g*1024 + ht*8 + d}, rr = g*8+d) into LDS, once
  for (int c = tid; c < 4096; c += 256) {
    const int rr = c >> 7;                       // 0..31
    const int cc = (c & 127) << 3;               // 0..1016 step 8
    const int gr = ((rr >> 3) << 10) + (ht << 3) + (rr & 7);
    *(s16x8*)(sW + rr * 1032 + cc) = *(const s16x8*)(Whh + ((size_t)gr << 10) + cc);
  }
  __syncthreads();

  const int batch_l = tid & 63, dgrp = tid >> 6; // thread owns 2 dims of 1 batch
  const int b_g = (bt << 6) + batch_l;
  float cst[2] = {0.f, 0.f};
  float xgv[4][2];

  const int T = BEAT ? 512 : 32;
  const u16* hbufs[2] = {hbuf0, hbuf1};

  for (int t = 0; t < T; ++t) {
    const u16* hp = hbufs[t & 1];
    u16* hn = const_cast<u16*>(hbufs[(t + 1) & 1]);

    // ---------- overlap zone: barrier-independent work ----------
    if (!BEAT || (t & 15) == 0) {   // lat-projection slice (incl. bias), fp32
      const int mrow = BEAT ? (t >> 4) : t;
      const float* xr = xg + (size_t)(b_g * 32 + mrow) * 4096 + (ht << 3) + (dgrp << 1);
      #pragma unroll
      for (int g = 0; g < 4; ++g)
        #pragma unroll
        for (int j = 0; j < 2; ++j) xgv[g][j] = xr[g * 1024 + j];
    }

    f32x4 acc[2];
    { f32x4 z = {0.f,0.f,0.f,0.f}; acc[0] = z; acc[1] = z; }

    if (BEAT) {  // beat-input projection: inp[bt-tile, t, :] @ WihB^T (K=128), h-independent
      #pragma unroll
      for (int kc = 0; kc < 4; ++kc) {
        const int k = (kc << 5) + (quad << 3);
        // B rows for chunk c: global row = (c*2 + (l15>>3))*1024 + ht*8 + (l15&7)
        const int r0 = (((l15 >> 3) << 10) + (ht << 3) + (l15 & 7));
        s16x8 bfr0 = *(const s16x8*)(WihB + (size_t)r0 * 128 + k);
        s16x8 bfr1 = *(const s16x8*)(WihB + (size_t)(r0 + 2048) * 128 + k);
        s16x8 afr = *(const s16x8*)(inp + ((size_t)((bt << 6) + (wave << 4) + l15) * 512 + t) * 128 + k);
        acc[0] = MFMA(afr, bfr0, acc[0]);
        acc[1] = MFMA(afr, bfr1, acc[1]);
      }
    }

    // ---------- wait: all 128 blocks of this bt finished step t-1 ----------
    if (t) {
      if (tid == 0) {
        while (__hip_atomic_load(flg, __ATOMIC_RELAXED, SCOPE_AGENT) < (unsigned)t)
          __builtin_amdgcn_s_sleep(2);
        // ONE acquire per block per step: s_waitcnt + buffer_inv (L1+L2) so
        // plain cached loads below observe this step's LLC-resident h/ring.
        (void)__hip_atomic_load(flg, __ATOMIC_ACQUIRE, SCOPE_AGENT);
      }
      __syncthreads();
      __atomic_signal_fence(__ATOMIC_SEQ_CST);
    }

    // ---------- duty fused output projection, window [t-16, t-1] ----------
    if (BEAT && t && (t & 15) == 0 && ht < 16)
      oproj_step(aux, linW, linb, dout, bt, t - 16 + ht, wave, quad, l15);

    // ---------- recurrent GEMM: h(t-1) @ Whh^T, wave = batch-quarter, full K ----------
    {
      const u16* ap = hp + ((size_t)(bt << 6) << 10)
                    + (((size_t)(wave << 4) + l15) << 10) + (quad << 3);
      s16x8 pf[8];
      #pragma unroll
      for (int g = 0; g < 8; ++g)
        pf[g] = *(const s16x8*)(ap + (g << 5));

      const u16* sB0 = sW + (l15) * 1032 + (quad << 3);         // chunk0: gates 0-1
      const u16* sB1 = sW + (16 + l15) * 1032 + (quad << 3);    // chunk1: gates 2-3
      #pragma unroll
      for (int kc = 0; kc < 32; ++kc) {
        s16x8 bfr0 = *(const s16x8*)(sB0 + (kc << 5));
        s16x8 bfr1 = *(const s16x8*)(sB1 + (kc << 5));
        acc[0] = MFMA(pf[kc & 7], bfr0, acc[0]);
        acc[1] = MFMA(pf[kc & 7], bfr1, acc[1]);
        if (kc < 24)
          pf[kc & 7] = *(const s16x8*)(ap + ((kc + 8) << 5));
      }
    }

    // ---------- stash to LDS (transpose to per-batch layout); single barrier ----------
    #pragma unroll
    for (int c = 0; c < 2; ++c)
      #pragma unroll
      for (int r = 0; r < 4; ++r)
        sEx[((wave << 4) + (quad << 2) + r) * 33 + (c << 4) + l15] = acc[c][r];
    __syncthreads();

    // ---------- element-wise LSTM cell update (thread owns 2 dims of 1 batch) ----------
    float hv[2], tv[2];
    {
      const int bo = batch_l * 33;
      #pragma unroll
      for (int j = 0; j < 2; ++j) {
        const int d = (dgrp << 1) + j;                 // local dim 0..7
        const float pi  = sEx[bo + d]        + xgv[0][j];   // gate0: chunk0 half0
        const float pf_ = sEx[bo + 8 + d]    + xgv[1][j];   // gate1: chunk0 half1
        const float pg  = sEx[bo + 16 + d]   + xgv[2][j];   // gate2: chunk1 half0
        const float po  = sEx[bo + 24 + d]   + xgv[3][j];   // gate3: chunk1 half1
        const float iv = sigf(pi), fv = sigf(pf_), gv = tanh_(pg), ov = sigf(po);
        cst[j] = fv * cst[j] + iv * gv;
        hv[j] = ov * tanh_(cst[j]);
        tv[j] = tanh_(hv[j]);
      }
    }
    u32 hpk = (u32)f2bf(hv[0]) | ((u32)f2bf(hv[1]) << 16);
    u32 tpk = (u32)f2bf(tv[0]) | ((u32)f2bf(tv[1]) << 16);
    cstore32((u32*)(hn + ((size_t)b_g << 10) + (ht << 3) + (dgrp << 1)), hpk);
    if (BEAT)
      cstore32((u32*)(aux + ((size_t)((t & 31) * 256 + b_g) << 10) + (ht << 3) + (dgrp << 1)), tpk);
    else
      cstore32((u32*)(aux + ((size_t)(b_g * 32 + t) << 10) + (ht << 3) + (dgrp << 1)), tpk);

    // ---------- arrive: syncthreads drains all threads' stores, then signal ----------
    __syncthreads();
    if (tid == 0) {
      const unsigned old = __hip_atomic_fetch_add(arr, 1u, __ATOMIC_RELAXED, SCOPE_AGENT);
      if (old == (unsigned)((t + 1) * 128 - 1))
        __hip_atomic_store(flg, (unsigned)(t + 1), __ATOMIC_RELAXED, SCOPE_AGENT);
    }
  }

  // ---------- tail: final output-projection window [T-16, T-1] ----------
  if (BEAT) {
    if (tid == 0) {
      while (__hip_atomic_load(flg, __ATOMIC_RELAXED, SCOPE_AGENT) < (unsigned)T)
        __builtin_amdgcn_s_sleep(2);
      (void)__hip_atomic_load(flg, __ATOMIC_ACQUIRE, SCOPE_AGENT);
    }
    __syncthreads();
    __atomic_signal_fence(__ATOMIC_SEQ_CST);
    if (ht < 16)
      oproj_step(aux, linW, linb, dout, bt, T - 16 + ht, wave, quad, l15);
  }
}

// ================= launcher =================
extern "C" void kernel_launch(void* const* d_in, const int* in_sizes, int n_in,
                              void* d_out, int out_size, void* d_ws, size_t ws_size,
                              hipStream_t stream) {
  (void)in_sizes; (void)n_in; (void)out_size; (void)ws_size;
  const float* latent = (const float*)d_in[0];
  const float* inputs = (const float*)d_in[1];
  const float* mWih   = (const float*)d_in[2];
  const float* mWhh   = (const float*)d_in[3];
  const float* mb     = (const float*)d_in[4];
  const float* bWih   = (const float*)d_in[5];
  const float* bWhh   = (const float*)d_in[6];
  const float* bb     = (const float*)d_in[7];
  const float* linW   = (const float*)d_in[8];
  const float* linb   = (const float*)d_in[9];
  char* ws = (char*)d_ws;

  float* xg    = (float*)(ws + OFF_XG);
  u16* latb    = (u16*)(ws + OFF_LATB);
  u16* inpb    = (u16*)(ws + OFF_INPB);
  u16* mwihb   = (u16*)(ws + OFF_MWIH);
  u16* mwhhb   = (u16*)(ws + OFF_MWHH);
  u16* bwab    = (u16*)(ws + OFF_BWA);
  u16* bwbb    = (u16*)(ws + OFF_BWB);
  u16* bwhhb   = (u16*)(ws + OFF_BWHH);
  u16* linwb   = (u16*)(ws + OFF_LINW);
  u16* latT    = (u16*)(ws + OFF_LAT);
  u16* hm      = (u16*)(ws + OFF_HM);
  u16* hb      = (u16*)(ws + OFF_HB);
  u16* ring    = (u16*)(ws + OFF_RING);
  unsigned* cs = (unsigned*)(ws + OFF_CTR);

  constexpr unsigned SMEM = 32 * 1032 * 2 + 64 * 33 * 4;  // 74,496 B (2 blocks/CU)
  hipFuncSetAttribute((const void*)(&lstm_rec<false>),
                      hipFuncAttributeMaxDynamicSharedMemorySize, (int)SMEM);
  hipFuncSetAttribute((const void*)(&lstm_rec<true>),
                      hipFuncAttributeMaxDynamicSharedMemorySize, (int)SMEM);

  // 1) prep: casts + splits + zero state/counters
  {
    const size_t total = 37356032ull;
    const int blocks = (int)((total + 255) / 256);
    prep_kernel<<<blocks, 256, 0, stream>>>(ws, latent, inputs, mWih, mWhh, bWih, bWhh, linW);
  }
  // 2) measure input projection: xg = latent @ mWih^T + mb   [8192x4096], K=512
  gemm_bt_bias<<<2048, 256, 0, stream>>>(latb, mwihb, mb, xg, 512, 4096);

  // 3) measure LSTM (T=32), writes lat = tanh(h)
  {
    const u16* a_whh = mwhhb; const float* a_xg = xg; const u16* a_wib = bwbb;
    const u16* a_inp = inpb;  const u16* a_lw = linwb; const float* a_lb = linb;
    u16* a_h0 = hm; u16* a_h1 = hm + Bz * Hz; u16* a_aux = latT;
    float* a_do = (float*)d_out; unsigned* a_ct = cs;
    void* margs[] = {&a_whh, &a_xg, &a_wib, &a_inp, &a_lw, &a_lb,
                     &a_h0, &a_h1, &a_aux, &a_do, &a_ct};
    hipError_t e = hipLaunchCooperativeKernel((const void*)(&lstm_rec<false>),
                                              dim3(512), dim3(256), margs, SMEM, stream);
    if (e != hipSuccess) {
      // fallback: plain launch (74.5KB LDS + VGPR<=128 -> 2/CU, 512 co-resident)
      lstm_rec<false><<<512, 256, SMEM, stream>>>(mwhhb, xg, bwbb, inpb, linwb, linb,
                                                  hm, hm + Bz * Hz, latT,
                                                  (float*)d_out, cs);
    }
  }
  // 4) beat lat projection: xg = lat @ bWih[:, :1024]^T + bb   [8192x4096], K=1024
  gemm_bt_bias<<<2048, 256, 0, stream>>>(latT, bwab, bb, xg, 1024, 4096);

  // 5) beat LSTM (T=512) with fused input-projection + fused output linear
  {
    const u16* a_whh = bwhhb; const float* a_xg = xg; const u16* a_wib = bwbb;
    const u16* a_inp = inpb;  const u16* a_lw = linwb; const float* a_lb = linb;
    u16* a_h0 = hb; u16* a_h1 = hb + Bz * Hz; u16* a_aux = ring;
    float* a_do = (float*)d_out; unsigned* a_ct = cs + 256;
    void* bargs[] = {&a_whh, &a_xg, &a_wib, &a_inp, &a_lw, &a_lb,
                     &a_h0, &a_h1, &a_aux, &a_do, &a_ct};
    hipError_t e = hipLaunchCooperativeKernel((const void*)(&lstm_rec<true>),
                                              dim3(512), dim3(256), bargs, SMEM, stream);
    if (e != hipSuccess) {
      lstm_rec<true><<<512, 256, SMEM, stream>>>(bwhhb, xg, bwbb, inpb, linwb, linb,
                                                 hb, hb + Bz * Hz, ring,
                                                 (float*)d_out, cs + 256);
    }
  }
}

// Round 7
// 9340.105 us; speedup vs baseline: 2.3259x; 1.3397x over previous
//
#include <hip/hip_runtime.h>
#include <stdint.h>

typedef short s16x8 __attribute__((ext_vector_type(8)));
typedef float f32x4 __attribute__((ext_vector_type(4)));
typedef unsigned short u16;
typedef unsigned int u32;
typedef unsigned long long u64;

#define DEV static __device__ __forceinline__
#define SCOPE_AGENT __HIP_MEMORY_SCOPE_AGENT

DEV u16 f2bf(float f) {
  unsigned u = __float_as_uint(f);
  u = (u + 0x7FFFu + ((u >> 16) & 1u)) >> 16;   // RNE
  return (u16)u;
}
DEV float sigf(float x) { return 1.0f / (1.0f + __expf(-x)); }
DEV float tanh_(float x) { float e = __expf(2.0f * x); return 1.0f - 2.0f / (e + 1.0f); }
DEV f32x4 MFMA(s16x8 a, s16x8 b, f32x4 c) {
  return __builtin_amdgcn_mfma_f32_16x16x32_bf16(a, b, c, 0, 0, 0);
}
// cache-bypassing relaxed atomics: visible at coherence point, no L2 flush
DEV void cstore32(u32* p, u32 v) {
  __hip_atomic_store(p, v, __ATOMIC_RELAXED, SCOPE_AGENT);
}

// ---------------- problem dims ----------------
constexpr int Bz = 256, INz = 512, Hz = 1024, Oz = 128;
constexpr int G4 = 4096;     // 4*H
constexpr int TB = 512;      // beat timesteps (M*S)
constexpr int BM = 8192;     // B*M rows

// ---------------- workspace layout (bytes) ----------------
constexpr size_t OFF_XG   = 0;                                   // f32 [8192][4096]
constexpr size_t OFF_LATB = OFF_XG   + (size_t)BM * G4 * 4;      // bf16 [8192][512]
constexpr size_t OFF_INPB = OFF_LATB + (size_t)BM * INz * 2;     // bf16 [256*512][128]
constexpr size_t OFF_MWIH = OFF_INPB + (size_t)Bz * TB * Oz * 2; // bf16 [4096][512]
constexpr size_t OFF_MWHH = OFF_MWIH + (size_t)G4 * INz * 2;     // bf16 [4096][1024]
constexpr size_t OFF_BWA  = OFF_MWHH + (size_t)G4 * Hz * 2;      // bf16 [4096][1024]
constexpr size_t OFF_BWB  = OFF_BWA  + (size_t)G4 * Hz * 2;      // bf16 [4096][128]
constexpr size_t OFF_BWHH = OFF_BWB  + (size_t)G4 * Oz * 2;      // bf16 [4096][1024]
constexpr size_t OFF_LINW = OFF_BWHH + (size_t)G4 * Hz * 2;      // bf16 [128][1024]
constexpr size_t OFF_LAT  = OFF_LINW + (size_t)Oz * Hz * 2;      // bf16 [8192][1024]
constexpr size_t OFF_HM   = OFF_LAT  + (size_t)BM * Hz * 2;      // bf16 2x tile-major 512KB
constexpr size_t OFF_HB   = OFF_HM   + (size_t)2 * Bz * Hz * 2;  // bf16 2x tile-major 512KB
constexpr size_t OFF_RING = OFF_HB   + (size_t)2 * Bz * Hz * 2;  // bf16 [32] tile-major slots
constexpr size_t OFF_CTR  = OFF_RING + (size_t)32 * Bz * Hz * 2; // counters (512 u32 = 2KB)

// ================= prep: casts / splits / zeroing =================
__global__ __launch_bounds__(256) void prep_kernel(
    char* __restrict__ ws, const float* __restrict__ latent,
    const float* __restrict__ inputs, const float* __restrict__ mWih,
    const float* __restrict__ mWhh, const float* __restrict__ bWih,
    const float* __restrict__ bWhh, const float* __restrict__ linW)
{
  size_t i = (size_t)blockIdx.x * 256 + threadIdx.x;
  const size_t n0 = (size_t)BM * INz;
  const size_t n1 = (size_t)Bz * TB * Oz;
  const size_t n2 = (size_t)G4 * INz;
  const size_t n3 = (size_t)G4 * Hz;
  const size_t n4 = (size_t)G4 * (Hz + Oz);
  const size_t n5 = (size_t)G4 * Hz;
  const size_t n6 = (size_t)Oz * Hz;
  const size_t n7 = (size_t)2 * Bz * Hz;
  const size_t n8 = (size_t)2 * Bz * Hz;
  const size_t n9 = 512;
  if (i < n0) { ((u16*)(ws + OFF_LATB))[i] = f2bf(latent[i]); return; } i -= n0;
  if (i < n1) { ((u16*)(ws + OFF_INPB))[i] = f2bf(inputs[i]); return; } i -= n1;
  if (i < n2) { ((u16*)(ws + OFF_MWIH))[i] = f2bf(mWih[i]);   return; } i -= n2;
  if (i < n3) { ((u16*)(ws + OFF_MWHH))[i] = f2bf(mWhh[i]);   return; } i -= n3;
  if (i < n4) {
    size_t r = i / 1152, c = i - r * 1152;
    float v = bWih[i];
    if (c < 1024) ((u16*)(ws + OFF_BWA))[r * 1024 + c] = f2bf(v);
    else          ((u16*)(ws + OFF_BWB))[r * 128 + (c - 1024)] = f2bf(v);
    return;
  } i -= n4;
  if (i < n5) { ((u16*)(ws + OFF_BWHH))[i] = f2bf(bWhh[i]);   return; } i -= n5;
  if (i < n6) { ((u16*)(ws + OFF_LINW))[i] = f2bf(linW[i]);   return; } i -= n6;
  if (i < n7) { ((u16*)(ws + OFF_HM))[i] = 0; return; } i -= n7;
  if (i < n8) { ((u16*)(ws + OFF_HB))[i] = 0; return; } i -= n8;
  if (i < n9) { ((unsigned*)(ws + OFF_CTR))[i] = 0; return; }
}

// ================= projection GEMM: C[M][N](f32) = A[M][K](bf16) @ B[N][K]^T + bias =================
__global__ __launch_bounds__(256) void gemm_bt_bias(
    const u16* __restrict__ A, const u16* __restrict__ Bw,
    const float* __restrict__ bias, float* __restrict__ C, int K, int Ndim)
{
  __shared__ u16 As[128 * 40];
  __shared__ u16 Bs[128 * 40];
  const int bx = blockIdx.x & 63;
  const int by = blockIdx.x >> 6;
  const int m0 = bx * 128, n0 = by * 128;
  const int tid = threadIdx.x, lane = tid & 63, wave = tid >> 6;
  const int quad = lane >> 4, l15 = lane & 15;
  const int wm = wave & 1, wn = wave >> 1;
  const int srow = tid >> 1, shalf = tid & 1;

  f32x4 acc[4][4];
  #pragma unroll
  for (int mi = 0; mi < 4; ++mi)
    #pragma unroll
    for (int ni = 0; ni < 4; ++ni) { f32x4 z = {0.f,0.f,0.f,0.f}; acc[mi][ni] = z; }

  const int KC = K >> 5;
  for (int kc = 0; kc < KC; ++kc) {
    const size_t ka = (size_t)(m0 + srow) * K + kc * 32 + shalf * 16;
    s16x8 va0 = *(const s16x8*)(A + ka);
    s16x8 va1 = *(const s16x8*)(A + ka + 8);
    const size_t kb = (size_t)(n0 + srow) * K + kc * 32 + shalf * 16;
    s16x8 vb0 = *(const s16x8*)(Bw + kb);
    s16x8 vb1 = *(const s16x8*)(Bw + kb + 8);
    __syncthreads();
    *(s16x8*)(As + srow * 40 + shalf * 16)     = va0;
    *(s16x8*)(As + srow * 40 + shalf * 16 + 8) = va1;
    *(s16x8*)(Bs + srow * 40 + shalf * 16)     = vb0;
    *(s16x8*)(Bs + srow * 40 + shalf * 16 + 8) = vb1;
    __syncthreads();
    s16x8 af[4], bf[4];
    #pragma unroll
    for (int mi = 0; mi < 4; ++mi)
      af[mi] = *(const s16x8*)(As + (wm * 64 + mi * 16 + l15) * 40 + quad * 8);
    #pragma unroll
    for (int ni = 0; ni < 4; ++ni)
      bf[ni] = *(const s16x8*)(Bs + (wn * 64 + ni * 16 + l15) * 40 + quad * 8);
    #pragma unroll
    for (int mi = 0; mi < 4; ++mi)
      #pragma unroll
      for (int ni = 0; ni < 4; ++ni)
        acc[mi][ni] = MFMA(af[mi], bf[ni], acc[mi][ni]);
  }
  #pragma unroll
  for (int mi = 0; mi < 4; ++mi)
    #pragma unroll
    for (int ni = 0; ni < 4; ++ni) {
      const int col = n0 + wn * 64 + ni * 16 + l15;
      const float bs = bias[col];
      #pragma unroll
      for (int r = 0; r < 4; ++r) {
        const int row = m0 + wm * 64 + mi * 16 + quad * 4 + r;
        C[(size_t)row * Ndim + col] = acc[mi][ni][r] + bs;
      }
    }
}

// ---- duty output projection for one timestep t0 (64 batches x 128 out, K=1024) ----
// ring is tile-major: [slot][bt][ht][batch 0..63][8 dims]; A-fragment = one 16B load.
DEV void oproj_step(const u16* __restrict__ aux, const u16* __restrict__ linW,
                    const float* __restrict__ linb, float* __restrict__ dout,
                    int bt, int t0, int wave, int quad, int l15)
{
  const u16* base = aux + (size_t)(t0 & 31) * 262144 + ((size_t)bt << 16);
  const u16* orp = base + (((quad << 6) + (wave << 4) + l15) << 3);
  const u16* lp[8];
  #pragma unroll
  for (int nt = 0; nt < 8; ++nt)
    lp[nt] = linW + (((size_t)(nt << 4) + l15) << 10) + (quad << 3);
  f32x4 oacc[8];
  #pragma unroll
  for (int nt = 0; nt < 8; ++nt) { f32x4 z = {0.f,0.f,0.f,0.f}; oacc[nt] = z; }
  s16x8 opf[4];
  #pragma unroll
  for (int g = 0; g < 4; ++g)
    opf[g] = *(const s16x8*)(orp + (g << 11));
  #pragma unroll
  for (int kc = 0; kc < 32; ++kc) {
    const s16x8 a = opf[kc & 3];
    #pragma unroll
    for (int nt = 0; nt < 8; ++nt) {
      s16x8 b = *(const s16x8*)(lp[nt] + (kc << 5));
      oacc[nt] = MFMA(a, b, oacc[nt]);
    }
    if (kc < 28)
      opf[kc & 3] = *(const s16x8*)(orp + ((size_t)(kc + 4) << 11));
  }
  #pragma unroll
  for (int nt = 0; nt < 8; ++nt) {
    const int col = (nt << 4) + l15;
    const float bs = linb[col];
    #pragma unroll
    for (int r = 0; r < 4; ++r) {
      const int bg2 = (bt << 6) + (wave << 4) + (quad << 2) + r;
      dout[((size_t)bg2 * 512 + t0) * 128 + col] = oacc[nt][r] + bs;
    }
  }
}

// ================= persistent recurrent LSTM =================
// R10 = R9 + ONE-LINE FIX: ring write slot stride was 65536 u32 (256KB) while the
// oproj read used 262144 u16 (512KB) -> odd slots aliased even slots' read regions.
// (R8/R9's bit-identical absmax 0.2368774 across two barrier protocols proved a
// deterministic addressing bug, not a sync race.) Correct stride: 131072 u32.
//  - h/ring TILE-MAJOR [bt][ht][batch64][dim8]; block output = contiguous 1KB tile,
//    LDS-staged then 256x4B coalesced stores (kills R7's measured 8x write amp).
//  - barrier: R7-proven fetch_add arrive + last-arriver flag + tid0 spin +
//    ONE agent-acquire (buffer_inv) per block per step.
template<bool BEAT>
__global__ __launch_bounds__(256, 2) void lstm_rec(
    const u16* __restrict__ Whh,   // [4096][1024] bf16
    const float* __restrict__ xg,  // [8192][4096] f32 rows = b*32 + m
    const u16* __restrict__ WihB,  // [4096][128]  (beat)
    const u16* __restrict__ inp,   // [256*512][128] (beat)
    const u16* __restrict__ linW,  // [128][1024]  (beat)
    const float* __restrict__ linb,// [128]        (beat)
    u16* __restrict__ hbuf0, u16* __restrict__ hbuf1,
    u16* __restrict__ aux,         // measure: lat [8192][1024] row-major; beat: ring tile-major
    float* __restrict__ dout,      // beat: [256][512][128]
    unsigned* __restrict__ ctr)    // per-phase counter region (measure cs, beat cs+256)
{
  extern __shared__ char smem[];
  u16* sW = (u16*)smem;                          // 32 rows x (1024+8) = 66048 B
  float* sEx = (float*)(smem + 66048);           // 64 x 33 floats = 8448 B
  u32* sSt = (u32*)(smem + 66048 + 8448);        // 512 u32 staging = 2048 B

  const int blk = blockIdx.x;
  const int bt = blk >> 7, ht = blk & 127;       // 4 groups x 128 blocks; 8 h-dims each
  const int tid = threadIdx.x;
  const int wave = tid >> 6, lane = tid & 63;
  const int quad = lane >> 4, l15 = lane & 15;

  // per-batch-tile barrier: arrive counter and go flag, 128B apart; groups 256B apart
  unsigned* const arr = ctr + (bt << 6);
  unsigned* const flg = arr + 32;

  // stage Whh slice (rows {g*1024 + ht*8 + d}, rr = g*8+d) into LDS, once
  for (int c = tid; c < 4096; c += 256) {
    const int rr = c >> 7;                       // 0..31
    const int cc = (c & 127) << 3;               // 0..1016 step 8
    const int gr = ((rr >> 3) << 10) + (ht << 3) + (rr & 7);
    *(s16x8*)(sW + rr * 1032 + cc) = *(const s16x8*)(Whh + ((size_t)gr << 10) + cc);
  }
  __syncthreads();

  const int batch_l = tid & 63, dgrp = tid >> 6; // thread owns 2 dims of 1 batch
  const int b_g = (bt << 6) + batch_l;
  float cst[2] = {0.f, 0.f};
  float xgv[4][2];

  const int T = BEAT ? 512 : 32;
  const u16* hbufs[2] = {hbuf0, hbuf1};

  for (int t = 0; t < T; ++t) {
    const u16* hp = hbufs[t & 1];
    u16* hn = const_cast<u16*>(hbufs[(t + 1) & 1]);

    // ---------- overlap zone: barrier-independent work ----------
    if (!BEAT || (t & 15) == 0) {   // lat-projection slice (incl. bias), fp32
      const int mrow = BEAT ? (t >> 4) : t;
      const float* xr = xg + (size_t)(b_g * 32 + mrow) * 4096 + (ht << 3) + (dgrp << 1);
      #pragma unroll
      for (int g = 0; g < 4; ++g)
        #pragma unroll
        for (int j = 0; j < 2; ++j) xgv[g][j] = xr[g * 1024 + j];
    }

    f32x4 acc[2];
    { f32x4 z = {0.f,0.f,0.f,0.f}; acc[0] = z; acc[1] = z; }

    if (BEAT) {  // beat-input projection: inp[bt-tile, t, :] @ WihB^T (K=128), h-independent
      #pragma unroll
      for (int kc = 0; kc < 4; ++kc) {
        const int k = (kc << 5) + (quad << 3);
        const int r0 = (((l15 >> 3) << 10) + (ht << 3) + (l15 & 7));
        s16x8 bfr0 = *(const s16x8*)(WihB + (size_t)r0 * 128 + k);
        s16x8 bfr1 = *(const s16x8*)(WihB + (size_t)(r0 + 2048) * 128 + k);
        s16x8 afr = *(const s16x8*)(inp + ((size_t)((bt << 6) + (wave << 4) + l15) * 512 + t) * 128 + k);
        acc[0] = MFMA(afr, bfr0, acc[0]);
        acc[1] = MFMA(afr, bfr1, acc[1]);
      }
    }

    // ---------- wait: all 128 blocks of this group finished step t-1 ----------
    if (t) {
      if (tid == 0) {
        while (__hip_atomic_load(flg, __ATOMIC_RELAXED, SCOPE_AGENT) < (unsigned)t)
          __builtin_amdgcn_s_sleep(2);
        // ONE acquire per block per step: s_waitcnt + buffer_inv (L1+L2) so
        // plain cached loads below observe this step's LLC-resident h/ring.
        (void)__hip_atomic_load(flg, __ATOMIC_ACQUIRE, SCOPE_AGENT);
      }
      __syncthreads();
      __atomic_signal_fence(__ATOMIC_SEQ_CST);
    }

    // ---------- duty fused output projection, window [t-16, t-1] ----------
    if (BEAT && t && (t & 15) == 0 && ht < 16)
      oproj_step(aux, linW, linb, dout, bt, t - 16 + ht, wave, quad, l15);

    // ---------- recurrent GEMM: h(t-1) @ Whh^T, tile-major A, full K per wave ----------
    {
      const u16* hbase = hp + ((size_t)bt << 16);
      const u16* ap = hbase + (((quad << 6) + (wave << 4) + l15) << 3);
      s16x8 pf[8];
      #pragma unroll
      for (int g = 0; g < 8; ++g)
        pf[g] = *(const s16x8*)(ap + (g << 11));

      const u16* sB0 = sW + (l15) * 1032 + (quad << 3);         // gates 0-1
      const u16* sB1 = sW + (16 + l15) * 1032 + (quad << 3);    // gates 2-3
      #pragma unroll
      for (int kc = 0; kc < 32; ++kc) {
        s16x8 bfr0 = *(const s16x8*)(sB0 + (kc << 5));
        s16x8 bfr1 = *(const s16x8*)(sB1 + (kc << 5));
        acc[0] = MFMA(pf[kc & 7], bfr0, acc[0]);
        acc[1] = MFMA(pf[kc & 7], bfr1, acc[1]);
        if (kc < 24)
          pf[kc & 7] = *(const s16x8*)(ap + ((size_t)(kc + 8) << 11));
      }
    }

    // ---------- stash gate sums to LDS (transpose to per-batch layout) ----------
    #pragma unroll
    for (int c = 0; c < 2; ++c)
      #pragma unroll
      for (int r = 0; r < 4; ++r)
        sEx[((wave << 4) + (quad << 2) + r) * 33 + (c << 4) + l15] = acc[c][r];
    __syncthreads();

    // ---------- element-wise LSTM cell update (thread owns 2 dims of 1 batch) ----------
    float hv[2], tv[2];
    {
      const int bo = batch_l * 33;
      #pragma unroll
      for (int j = 0; j < 2; ++j) {
        const int d = (dgrp << 1) + j;                 // local dim 0..7
        const float pi  = sEx[bo + d]        + xgv[0][j];
        const float pf_ = sEx[bo + 8 + d]    + xgv[1][j];
        const float pg  = sEx[bo + 16 + d]   + xgv[2][j];
        const float po  = sEx[bo + 24 + d]   + xgv[3][j];
        const float iv = sigf(pi), fv = sigf(pf_), gv = tanh_(pg), ov = sigf(po);
        cst[j] = fv * cst[j] + iv * gv;
        hv[j] = ov * tanh_(cst[j]);
        tv[j] = tanh_(hv[j]);
      }
    }
    const u32 hpk = (u32)f2bf(hv[0]) | ((u32)f2bf(hv[1]) << 16);
    const u32 tpk = (u32)f2bf(tv[0]) | ((u32)f2bf(tv[1]) << 16);

    // stage into LDS in tile order [batch][dgrp], then coalesced 1KB store(s)
    sSt[batch_l * 4 + dgrp] = hpk;
    if (BEAT) sSt[256 + batch_l * 4 + dgrp] = tpk;
    __syncthreads();
    {
      u32* hdst = (u32*)hn + (((size_t)(bt << 7) + ht) << 8);
      cstore32(hdst + tid, sSt[tid]);
      if (BEAT) {
        // slot stride = 512KB = 131072 u32 (BUGFIX: was 65536 u32 in R8/R9)
        u32* rdst = (u32*)aux + (size_t)(t & 31) * 131072 + (((size_t)(bt << 7) + ht) << 8);
        cstore32(rdst + tid, sSt[256 + tid]);
      } else {
        // measure lat output stays row-major [8192][1024] for the following GEMM
        cstore32((u32*)(aux + ((size_t)(b_g * 32 + t) << 10) + (ht << 3) + (dgrp << 1)), tpk);
      }
    }

    // ---------- arrive: syncthreads drains stores; R7-proven fetch_add + flag ----------
    __syncthreads();
    if (tid == 0) {
      const unsigned old = __hip_atomic_fetch_add(arr, 1u, __ATOMIC_RELAXED, SCOPE_AGENT);
      if (old == (unsigned)((t + 1) * 128 - 1))
        __hip_atomic_store(flg, (unsigned)(t + 1), __ATOMIC_RELAXED, SCOPE_AGENT);
    }
  }

  // ---------- tail: final output-projection window [T-16, T-1] ----------
  if (BEAT) {
    if (tid == 0) {
      while (__hip_atomic_load(flg, __ATOMIC_RELAXED, SCOPE_AGENT) < (unsigned)T)
        __builtin_amdgcn_s_sleep(2);
      (void)__hip_atomic_load(flg, __ATOMIC_ACQUIRE, SCOPE_AGENT);
    }
    __syncthreads();
    __atomic_signal_fence(__ATOMIC_SEQ_CST);
    if (ht < 16)
      oproj_step(aux, linW, linb, dout, bt, T - 16 + ht, wave, quad, l15);
  }
}

// ================= launcher =================
extern "C" void kernel_launch(void* const* d_in, const int* in_sizes, int n_in,
                              void* d_out, int out_size, void* d_ws, size_t ws_size,
                              hipStream_t stream) {
  (void)in_sizes; (void)n_in; (void)out_size; (void)ws_size;
  const float* latent = (const float*)d_in[0];
  const float* inputs = (const float*)d_in[1];
  const float* mWih   = (const float*)d_in[2];
  const float* mWhh   = (const float*)d_in[3];
  const float* mb     = (const float*)d_in[4];
  const float* bWih   = (const float*)d_in[5];
  const float* bWhh   = (const float*)d_in[6];
  const float* bb     = (const float*)d_in[7];
  const float* linW   = (const float*)d_in[8];
  const float* linb   = (const float*)d_in[9];
  char* ws = (char*)d_ws;

  float* xg    = (float*)(ws + OFF_XG);
  u16* latb    = (u16*)(ws + OFF_LATB);
  u16* inpb    = (u16*)(ws + OFF_INPB);
  u16* mwihb   = (u16*)(ws + OFF_MWIH);
  u16* mwhhb   = (u16*)(ws + OFF_MWHH);
  u16* bwab    = (u16*)(ws + OFF_BWA);
  u16* bwbb    = (u16*)(ws + OFF_BWB);
  u16* bwhhb   = (u16*)(ws + OFF_BWHH);
  u16* linwb   = (u16*)(ws + OFF_LINW);
  u16* latT    = (u16*)(ws + OFF_LAT);
  u16* hm      = (u16*)(ws + OFF_HM);
  u16* hb      = (u16*)(ws + OFF_HB);
  u16* ring    = (u16*)(ws + OFF_RING);
  unsigned* cs = (unsigned*)(ws + OFF_CTR);

  constexpr unsigned SMEM = 66048 + 8448 + 2048;  // 76,544 B (2 blocks/CU)
  hipFuncSetAttribute((const void*)(&lstm_rec<false>),
                      hipFuncAttributeMaxDynamicSharedMemorySize, (int)SMEM);
  hipFuncSetAttribute((const void*)(&lstm_rec<true>),
                      hipFuncAttributeMaxDynamicSharedMemorySize, (int)SMEM);

  // 1) prep: casts + splits + zero state/counters
  {
    const size_t total = 37356032ull;
    const int blocks = (int)((total + 255) / 256);
    prep_kernel<<<blocks, 256, 0, stream>>>(ws, latent, inputs, mWih, mWhh, bWih, bWhh, linW);
  }
  // 2) measure input projection: xg = latent @ mWih^T + mb   [8192x4096], K=512
  gemm_bt_bias<<<2048, 256, 0, stream>>>(latb, mwihb, mb, xg, 512, 4096);

  // 3) measure LSTM (T=32), writes lat = tanh(h) (row-major)
  {
    const u16* a_whh = mwhhb; const float* a_xg = xg; const u16* a_wib = bwbb;
    const u16* a_inp = inpb;  const u16* a_lw = linwb; const float* a_lb = linb;
    u16* a_h0 = hm; u16* a_h1 = hm + Bz * Hz; u16* a_aux = latT;
    float* a_do = (float*)d_out; unsigned* a_ct = cs;
    void* margs[] = {&a_whh, &a_xg, &a_wib, &a_inp, &a_lw, &a_lb,
                     &a_h0, &a_h1, &a_aux, &a_do, &a_ct};
    hipError_t e = hipLaunchCooperativeKernel((const void*)(&lstm_rec<false>),
                                              dim3(512), dim3(256), margs, SMEM, stream);
    if (e != hipSuccess) {
      lstm_rec<false><<<512, 256, SMEM, stream>>>(mwhhb, xg, bwbb, inpb, linwb, linb,
                                                  hm, hm + Bz * Hz, latT,
                                                  (float*)d_out, cs);
    }
  }
  // 4) beat lat projection: xg = lat @ bWih[:, :1024]^T + bb   [8192x4096], K=1024
  gemm_bt_bias<<<2048, 256, 0, stream>>>(latT, bwab, bb, xg, 1024, 4096);

  // 5) beat LSTM (T=512) with fused input-projection + fused output linear
  {
    const u16* a_whh = bwhhb; const float* a_xg = xg; const u16* a_wib = bwbb;
    const u16* a_inp = inpb;  const u16* a_lw = linwb; const float* a_lb = linb;
    u16* a_h0 = hb; u16* a_h1 = hb + Bz * Hz; u16* a_aux = ring;
    float* a_do = (float*)d_out; unsigned* a_ct = cs + 256;
    void* bargs[] = {&a_whh, &a_xg, &a_wib, &a_inp, &a_lw, &a_lb,
                     &a_h0, &a_h1, &a_aux, &a_do, &a_ct};
    hipError_t e = hipLaunchCooperativeKernel((const void*)(&lstm_rec<true>),
                                              dim3(512), dim3(256), bargs, SMEM, stream);
    if (e != hipSuccess) {
      lstm_rec<true><<<512, 256, SMEM, stream>>>(bwhhb, xg, bwbb, inpb, linwb, linb,
                                                 hb, hb + Bz * Hz, ring,
                                                 (float*)d_out, cs + 256);
    }
  }
}

// Round 8
// 8447.355 us; speedup vs baseline: 2.5718x; 1.1057x over previous
//
#include <hip/hip_runtime.h>
#include <stdint.h>

typedef short s16x8 __attribute__((ext_vector_type(8)));
typedef float f32x4 __attribute__((ext_vector_type(4)));
typedef unsigned short u16;
typedef unsigned int u32;
typedef unsigned long long u64;

#define DEV static __device__ __forceinline__
#define SCOPE_AGENT __HIP_MEMORY_SCOPE_AGENT

DEV u16 f2bf(float f) {
  unsigned u = __float_as_uint(f);
  u = (u + 0x7FFFu + ((u >> 16) & 1u)) >> 16;   // RNE
  return (u16)u;
}
DEV float sigf(float x) { return 1.0f / (1.0f + __expf(-x)); }
DEV float tanh_(float x) { float e = __expf(2.0f * x); return 1.0f - 2.0f / (e + 1.0f); }
DEV f32x4 MFMA(s16x8 a, s16x8 b, f32x4 c) {
  return __builtin_amdgcn_mfma_f32_16x16x32_bf16(a, b, c, 0, 0, 0);
}
// cache-bypassing relaxed atomics: visible at coherence point, no L2 flush
DEV void cstore32(u32* p, u32 v) {
  __hip_atomic_store(p, v, __ATOMIC_RELAXED, SCOPE_AGENT);
}
DEV u32 cload32(const u32* p) {
  return __hip_atomic_load((u32*)p, __ATOMIC_RELAXED, SCOPE_AGENT);
}

// ---------------- problem dims ----------------
constexpr int Bz = 256, INz = 512, Hz = 1024, Oz = 128;
constexpr int G4 = 4096;     // 4*H
constexpr int TB = 512;      // beat timesteps (M*S)
constexpr int BM = 8192;     // B*M rows

// ---------------- workspace layout (bytes) ----------------
constexpr size_t OFF_XG   = 0;                                   // f32 [8192][4096]
constexpr size_t OFF_LATB = OFF_XG   + (size_t)BM * G4 * 4;      // bf16 [8192][512]
constexpr size_t OFF_INPB = OFF_LATB + (size_t)BM * INz * 2;     // bf16 [256*512][128]
constexpr size_t OFF_MWIH = OFF_INPB + (size_t)Bz * TB * Oz * 2; // bf16 [4096][512]
constexpr size_t OFF_MWHH = OFF_MWIH + (size_t)G4 * INz * 2;     // bf16 [4096][1024]
constexpr size_t OFF_BWA  = OFF_MWHH + (size_t)G4 * Hz * 2;      // bf16 [4096][1024]
constexpr size_t OFF_BWB  = OFF_BWA  + (size_t)G4 * Hz * 2;      // bf16 [4096][128]
constexpr size_t OFF_BWHH = OFF_BWB  + (size_t)G4 * Oz * 2;      // bf16 [4096][1024]
constexpr size_t OFF_LINW = OFF_BWHH + (size_t)G4 * Hz * 2;      // bf16 [128][1024]
constexpr size_t OFF_LAT  = OFF_LINW + (size_t)Oz * Hz * 2;      // bf16 [8192][1024]
constexpr size_t OFF_HM   = OFF_LAT  + (size_t)BM * Hz * 2;      // bf16 2x tile-major 512KB
constexpr size_t OFF_HB   = OFF_HM   + (size_t)2 * Bz * Hz * 2;  // bf16 2x tile-major 512KB
constexpr size_t OFF_RING = OFF_HB   + (size_t)2 * Bz * Hz * 2;  // bf16 [32] tile-major slots
constexpr size_t OFF_CTR  = OFF_RING + (size_t)32 * Bz * Hz * 2; // slot flags (1024 u32 = 4KB)

// ================= prep: casts / splits / zeroing =================
__global__ __launch_bounds__(256) void prep_kernel(
    char* __restrict__ ws, const float* __restrict__ latent,
    const float* __restrict__ inputs, const float* __restrict__ mWih,
    const float* __restrict__ mWhh, const float* __restrict__ bWih,
    const float* __restrict__ bWhh, const float* __restrict__ linW)
{
  size_t i = (size_t)blockIdx.x * 256 + threadIdx.x;
  const size_t n0 = (size_t)BM * INz;
  const size_t n1 = (size_t)Bz * TB * Oz;
  const size_t n2 = (size_t)G4 * INz;
  const size_t n3 = (size_t)G4 * Hz;
  const size_t n4 = (size_t)G4 * (Hz + Oz);
  const size_t n5 = (size_t)G4 * Hz;
  const size_t n6 = (size_t)Oz * Hz;
  const size_t n7 = (size_t)2 * Bz * Hz;
  const size_t n8 = (size_t)2 * Bz * Hz;
  const size_t n9 = 1024;
  if (i < n0) { ((u16*)(ws + OFF_LATB))[i] = f2bf(latent[i]); return; } i -= n0;
  if (i < n1) { ((u16*)(ws + OFF_INPB))[i] = f2bf(inputs[i]); return; } i -= n1;
  if (i < n2) { ((u16*)(ws + OFF_MWIH))[i] = f2bf(mWih[i]);   return; } i -= n2;
  if (i < n3) { ((u16*)(ws + OFF_MWHH))[i] = f2bf(mWhh[i]);   return; } i -= n3;
  if (i < n4) {
    size_t r = i / 1152, c = i - r * 1152;
    float v = bWih[i];
    if (c < 1024) ((u16*)(ws + OFF_BWA))[r * 1024 + c] = f2bf(v);
    else          ((u16*)(ws + OFF_BWB))[r * 128 + (c - 1024)] = f2bf(v);
    return;
  } i -= n4;
  if (i < n5) { ((u16*)(ws + OFF_BWHH))[i] = f2bf(bWhh[i]);   return; } i -= n5;
  if (i < n6) { ((u16*)(ws + OFF_LINW))[i] = f2bf(linW[i]);   return; } i -= n6;
  if (i < n7) { ((u16*)(ws + OFF_HM))[i] = 0; return; } i -= n7;
  if (i < n8) { ((u16*)(ws + OFF_HB))[i] = 0; return; } i -= n8;
  if (i < n9) { ((unsigned*)(ws + OFF_CTR))[i] = 0; return; }
}

// ================= projection GEMM: C[M][N](f32) = A[M][K](bf16) @ B[N][K]^T + bias =================
__global__ __launch_bounds__(256) void gemm_bt_bias(
    const u16* __restrict__ A, const u16* __restrict__ Bw,
    const float* __restrict__ bias, float* __restrict__ C, int K, int Ndim)
{
  __shared__ u16 As[128 * 40];
  __shared__ u16 Bs[128 * 40];
  const int bx = blockIdx.x & 63;
  const int by = blockIdx.x >> 6;
  const int m0 = bx * 128, n0 = by * 128;
  const int tid = threadIdx.x, lane = tid & 63, wave = tid >> 6;
  const int quad = lane >> 4, l15 = lane & 15;
  const int wm = wave & 1, wn = wave >> 1;
  const int srow = tid >> 1, shalf = tid & 1;

  f32x4 acc[4][4];
  #pragma unroll
  for (int mi = 0; mi < 4; ++mi)
    #pragma unroll
    for (int ni = 0; ni < 4; ++ni) { f32x4 z = {0.f,0.f,0.f,0.f}; acc[mi][ni] = z; }

  const int KC = K >> 5;
  for (int kc = 0; kc < KC; ++kc) {
    const size_t ka = (size_t)(m0 + srow) * K + kc * 32 + shalf * 16;
    s16x8 va0 = *(const s16x8*)(A + ka);
    s16x8 va1 = *(const s16x8*)(A + ka + 8);
    const size_t kb = (size_t)(n0 + srow) * K + kc * 32 + shalf * 16;
    s16x8 vb0 = *(const s16x8*)(Bw + kb);
    s16x8 vb1 = *(const s16x8*)(Bw + kb + 8);
    __syncthreads();
    *(s16x8*)(As + srow * 40 + shalf * 16)     = va0;
    *(s16x8*)(As + srow * 40 + shalf * 16 + 8) = va1;
    *(s16x8*)(Bs + srow * 40 + shalf * 16)     = vb0;
    *(s16x8*)(Bs + srow * 40 + shalf * 16 + 8) = vb1;
    __syncthreads();
    s16x8 af[4], bf[4];
    #pragma unroll
    for (int mi = 0; mi < 4; ++mi)
      af[mi] = *(const s16x8*)(As + (wm * 64 + mi * 16 + l15) * 40 + quad * 8);
    #pragma unroll
    for (int ni = 0; ni < 4; ++ni)
      bf[ni] = *(const s16x8*)(Bs + (wn * 64 + ni * 16 + l15) * 40 + quad * 8);
    #pragma unroll
    for (int mi = 0; mi < 4; ++mi)
      #pragma unroll
      for (int ni = 0; ni < 4; ++ni)
        acc[mi][ni] = MFMA(af[mi], bf[ni], acc[mi][ni]);
  }
  #pragma unroll
  for (int mi = 0; mi < 4; ++mi)
    #pragma unroll
    for (int ni = 0; ni < 4; ++ni) {
      const int col = n0 + wn * 64 + ni * 16 + l15;
      const float bs = bias[col];
      #pragma unroll
      for (int r = 0; r < 4; ++r) {
        const int row = m0 + wm * 64 + mi * 16 + quad * 4 + r;
        C[(size_t)row * Ndim + col] = acc[mi][ni][r] + bs;
      }
    }
}

// ---- duty output projection for one timestep t0 (64 batches x 128 out, K=1024) ----
// ring is tile-major: [slot][bt][ht][batch 0..63][8 dims]; A-fragment = one 16B load.
DEV void oproj_step(const u16* __restrict__ aux, const u16* __restrict__ linW,
                    const float* __restrict__ linb, float* __restrict__ dout,
                    int bt, int t0, int wave, int quad, int l15)
{
  const u16* base = aux + (size_t)(t0 & 31) * 262144 + ((size_t)bt << 16);
  const u16* orp = base + (((quad << 6) + (wave << 4) + l15) << 3);
  const u16* lp[8];
  #pragma unroll
  for (int nt = 0; nt < 8; ++nt)
    lp[nt] = linW + (((size_t)(nt << 4) + l15) << 10) + (quad << 3);
  f32x4 oacc[8];
  #pragma unroll
  for (int nt = 0; nt < 8; ++nt) { f32x4 z = {0.f,0.f,0.f,0.f}; oacc[nt] = z; }
  s16x8 opf[4];
  #pragma unroll
  for (int g = 0; g < 4; ++g)
    opf[g] = *(const s16x8*)(orp + (g << 11));
  #pragma unroll
  for (int kc = 0; kc < 32; ++kc) {
    const s16x8 a = opf[kc & 3];
    #pragma unroll
    for (int nt = 0; nt < 8; ++nt) {
      s16x8 b = *(const s16x8*)(lp[nt] + (kc << 5));
      oacc[nt] = MFMA(a, b, oacc[nt]);
    }
    if (kc < 28)
      opf[kc & 3] = *(const s16x8*)(orp + ((size_t)(kc + 4) << 11));
  }
  #pragma unroll
  for (int nt = 0; nt < 8; ++nt) {
    const int col = (nt << 4) + l15;
    const float bs = linb[col];
    #pragma unroll
    for (int r = 0; r < 4; ++r) {
      const int bg2 = (bt << 6) + (wave << 4) + (quad << 2) + r;
      dout[((size_t)bg2 * 512 + t0) * 128 + col] = oacc[nt][r] + bs;
    }
  }
}

// ================= persistent recurrent LSTM =================
// R11 deltas vs R10 (counters: WRITE amp fixed; residual = serial arrive->detect->
// inv->refill chain, MfmaUtil 5.9%):
//  - SLOT-FLAG barrier (R8 mechanism, exonerated by the R10 stride fix): arrive =
//    one fire-and-forget sc0sc1 store to the block's own slot (after __syncthreads
//    vmcnt drain = release); waiters poll 128 slots via 2 vector loads x 64 lanes +
//    __all. Removes the RMW round trip and the last-arriver flag hop.
//  - oproj moved PRE-WAIT: at step t, barrier(t-1) already guarantees steps <= t-2
//    visible; trigger t%16==2 (t>16), window [t-18, t-3]; tail covers [496,511].
//    Duty spike overlaps the spin instead of delaying the group.
//  - measure slots = ctr[0..511], beat slots = ctr[512..1023] (prep zeroes 1024).
template<bool BEAT>
__global__ __launch_bounds__(256, 2) void lstm_rec(
    const u16* __restrict__ Whh,   // [4096][1024] bf16
    const float* __restrict__ xg,  // [8192][4096] f32 rows = b*32 + m
    const u16* __restrict__ WihB,  // [4096][128]  (beat)
    const u16* __restrict__ inp,   // [256*512][128] (beat)
    const u16* __restrict__ linW,  // [128][1024]  (beat)
    const float* __restrict__ linb,// [128]        (beat)
    u16* __restrict__ hbuf0, u16* __restrict__ hbuf1,
    u16* __restrict__ aux,         // measure: lat [8192][1024] row-major; beat: ring tile-major
    float* __restrict__ dout,      // beat: [256][512][128]
    unsigned* __restrict__ ctr)    // per-phase slot region (512 u32)
{
  extern __shared__ char smem[];
  u16* sW = (u16*)smem;                          // 32 rows x (1024+8) = 66048 B
  float* sEx = (float*)(smem + 66048);           // 64 x 33 floats = 8448 B
  u32* sSt = (u32*)(smem + 66048 + 8448);        // 512 u32 staging = 2048 B

  const int blk = blockIdx.x;
  const int bt = blk >> 7, ht = blk & 127;       // 4 groups x 128 blocks; 8 h-dims each
  const int tid = threadIdx.x;
  const int wave = tid >> 6, lane = tid & 63;
  const int quad = lane >> 4, l15 = lane & 15;

  unsigned* const slots = ctr + (bt << 7);       // 128 slots (512 B) per group

  // stage Whh slice (rows {g*1024 + ht*8 + d}, rr = g*8+d) into LDS, once
  for (int c = tid; c < 4096; c += 256) {
    const int rr = c >> 7;                       // 0..31
    const int cc = (c & 127) << 3;               // 0..1016 step 8
    const int gr = ((rr >> 3) << 10) + (ht << 3) + (rr & 7);
    *(s16x8*)(sW + rr * 1032 + cc) = *(const s16x8*)(Whh + ((size_t)gr << 10) + cc);
  }
  __syncthreads();

  const int batch_l = tid & 63, dgrp = tid >> 6; // thread owns 2 dims of 1 batch
  const int b_g = (bt << 6) + batch_l;
  float cst[2] = {0.f, 0.f};
  float xgv[4][2];

  const int T = BEAT ? 512 : 32;
  const u16* hbufs[2] = {hbuf0, hbuf1};

  for (int t = 0; t < T; ++t) {
    const u16* hp = hbufs[t & 1];
    u16* hn = const_cast<u16*>(hbufs[(t + 1) & 1]);

    // ---------- overlap zone: barrier-independent work (pre-wait) ----------
    // duty fused output projection, window [t-18, t-3] (visible since barrier t-1)
    if (BEAT && (t & 15) == 2 && t > 16 && ht < 16)
      oproj_step(aux, linW, linb, dout, bt, t - 18 + ht, wave, quad, l15);

    if (!BEAT || (t & 15) == 0) {   // lat-projection slice (incl. bias), fp32
      const int mrow = BEAT ? (t >> 4) : t;
      const float* xr = xg + (size_t)(b_g * 32 + mrow) * 4096 + (ht << 3) + (dgrp << 1);
      #pragma unroll
      for (int g = 0; g < 4; ++g)
        #pragma unroll
        for (int j = 0; j < 2; ++j) xgv[g][j] = xr[g * 1024 + j];
    }

    f32x4 acc[2];
    { f32x4 z = {0.f,0.f,0.f,0.f}; acc[0] = z; acc[1] = z; }

    if (BEAT) {  // beat-input projection: inp[bt-tile, t, :] @ WihB^T (K=128), h-independent
      #pragma unroll
      for (int kc = 0; kc < 4; ++kc) {
        const int k = (kc << 5) + (quad << 3);
        const int r0 = (((l15 >> 3) << 10) + (ht << 3) + (l15 & 7));
        s16x8 bfr0 = *(const s16x8*)(WihB + (size_t)r0 * 128 + k);
        s16x8 bfr1 = *(const s16x8*)(WihB + (size_t)(r0 + 2048) * 128 + k);
        s16x8 afr = *(const s16x8*)(inp + ((size_t)((bt << 6) + (wave << 4) + l15) * 512 + t) * 128 + k);
        acc[0] = MFMA(afr, bfr0, acc[0]);
        acc[1] = MFMA(afr, bfr1, acc[1]);
      }
    }

    // ---------- wait: all 128 blocks of this group finished step t-1 ----------
    if (t) {
      const unsigned tgt = (unsigned)t;
      if (tid < 64) {
        for (;;) {
          unsigned a = cload32(slots + tid);
          unsigned b = cload32(slots + 64 + tid);
          if (__all(a >= tgt && b >= tgt)) break;
          __builtin_amdgcn_s_sleep(2);
        }
        if (tid == 0)  // one acquire per block per step: s_waitcnt + buffer_inv
          (void)__hip_atomic_load(slots, __ATOMIC_ACQUIRE, SCOPE_AGENT);
      }
      __syncthreads();
      __atomic_signal_fence(__ATOMIC_SEQ_CST);
    }

    // ---------- recurrent GEMM: h(t-1) @ Whh^T, tile-major A, full K per wave ----------
    {
      const u16* hbase = hp + ((size_t)bt << 16);
      const u16* ap = hbase + (((quad << 6) + (wave << 4) + l15) << 3);
      s16x8 pf[8];
      #pragma unroll
      for (int g = 0; g < 8; ++g)
        pf[g] = *(const s16x8*)(ap + (g << 11));

      const u16* sB0 = sW + (l15) * 1032 + (quad << 3);         // gates 0-1
      const u16* sB1 = sW + (16 + l15) * 1032 + (quad << 3);    // gates 2-3
      #pragma unroll
      for (int kc = 0; kc < 32; ++kc) {
        s16x8 bfr0 = *(const s16x8*)(sB0 + (kc << 5));
        s16x8 bfr1 = *(const s16x8*)(sB1 + (kc << 5));
        acc[0] = MFMA(pf[kc & 7], bfr0, acc[0]);
        acc[1] = MFMA(pf[kc & 7], bfr1, acc[1]);
        if (kc < 24)
          pf[kc & 7] = *(const s16x8*)(ap + ((size_t)(kc + 8) << 11));
      }
    }

    // ---------- stash gate sums to LDS (transpose to per-batch layout) ----------
    #pragma unroll
    for (int c = 0; c < 2; ++c)
      #pragma unroll
      for (int r = 0; r < 4; ++r)
        sEx[((wave << 4) + (quad << 2) + r) * 33 + (c << 4) + l15] = acc[c][r];
    __syncthreads();

    // ---------- element-wise LSTM cell update (thread owns 2 dims of 1 batch) ----------
    float hv[2], tv[2];
    {
      const int bo = batch_l * 33;
      #pragma unroll
      for (int j = 0; j < 2; ++j) {
        const int d = (dgrp << 1) + j;                 // local dim 0..7
        const float pi  = sEx[bo + d]        + xgv[0][j];
        const float pf_ = sEx[bo + 8 + d]    + xgv[1][j];
        const float pg  = sEx[bo + 16 + d]   + xgv[2][j];
        const float po  = sEx[bo + 24 + d]   + xgv[3][j];
        const float iv = sigf(pi), fv = sigf(pf_), gv = tanh_(pg), ov = sigf(po);
        cst[j] = fv * cst[j] + iv * gv;
        hv[j] = ov * tanh_(cst[j]);
        tv[j] = tanh_(hv[j]);
      }
    }
    const u32 hpk = (u32)f2bf(hv[0]) | ((u32)f2bf(hv[1]) << 16);
    const u32 tpk = (u32)f2bf(tv[0]) | ((u32)f2bf(tv[1]) << 16);

    // stage into LDS in tile order [batch][dgrp], then coalesced 1KB store(s)
    sSt[batch_l * 4 + dgrp] = hpk;
    if (BEAT) sSt[256 + batch_l * 4 + dgrp] = tpk;
    __syncthreads();
    {
      u32* hdst = (u32*)hn + (((size_t)(bt << 7) + ht) << 8);
      cstore32(hdst + tid, sSt[tid]);
      if (BEAT) {
        // slot stride = 512KB = 131072 u32
        u32* rdst = (u32*)aux + (size_t)(t & 31) * 131072 + (((size_t)(bt << 7) + ht) << 8);
        cstore32(rdst + tid, sSt[256 + tid]);
      } else {
        // measure lat output stays row-major [8192][1024] for the following GEMM
        cstore32((u32*)(aux + ((size_t)(b_g * 32 + t) << 10) + (ht << 3) + (dgrp << 1)), tpk);
      }
    }

    // ---------- arrive: syncthreads drains stores (release), then slot store ----------
    __syncthreads();
    if (tid == 0)
      cstore32(slots + ht, (unsigned)(t + 1));
  }

  // ---------- tail: final output-projection window [496, 511] ----------
  if (BEAT) {
    const unsigned tgt = (unsigned)T;
    if (tid < 64) {
      for (;;) {
        unsigned a = cload32(slots + tid);
        unsigned b = cload32(slots + 64 + tid);
        if (__all(a >= tgt && b >= tgt)) break;
        __builtin_amdgcn_s_sleep(2);
      }
      if (tid == 0)
        (void)__hip_atomic_load(slots, __ATOMIC_ACQUIRE, SCOPE_AGENT);
    }
    __syncthreads();
    __atomic_signal_fence(__ATOMIC_SEQ_CST);
    if (ht < 16)
      oproj_step(aux, linW, linb, dout, bt, T - 16 + ht, wave, quad, l15);
  }
}

// ================= launcher =================
extern "C" void kernel_launch(void* const* d_in, const int* in_sizes, int n_in,
                              void* d_out, int out_size, void* d_ws, size_t ws_size,
                              hipStream_t stream) {
  (void)in_sizes; (void)n_in; (void)out_size; (void)ws_size;
  const float* latent = (const float*)d_in[0];
  const float* inputs = (const float*)d_in[1];
  const float* mWih   = (const float*)d_in[2];
  const float* mWhh   = (const float*)d_in[3];
  const float* mb     = (const float*)d_in[4];
  const float* bWih   = (const float*)d_in[5];
  const float* bWhh   = (const float*)d_in[6];
  const float* bb     = (const float*)d_in[7];
  const float* linW   = (const float*)d_in[8];
  const float* linb   = (const float*)d_in[9];
  char* ws = (char*)d_ws;

  float* xg    = (float*)(ws + OFF_XG);
  u16* latb    = (u16*)(ws + OFF_LATB);
  u16* inpb    = (u16*)(ws + OFF_INPB);
  u16* mwihb   = (u16*)(ws + OFF_MWIH);
  u16* mwhhb   = (u16*)(ws + OFF_MWHH);
  u16* bwab    = (u16*)(ws + OFF_BWA);
  u16* bwbb    = (u16*)(ws + OFF_BWB);
  u16* bwhhb   = (u16*)(ws + OFF_BWHH);
  u16* linwb   = (u16*)(ws + OFF_LINW);
  u16* latT    = (u16*)(ws + OFF_LAT);
  u16* hm      = (u16*)(ws + OFF_HM);
  u16* hb      = (u16*)(ws + OFF_HB);
  u16* ring    = (u16*)(ws + OFF_RING);
  unsigned* cs = (unsigned*)(ws + OFF_CTR);

  constexpr unsigned SMEM = 66048 + 8448 + 2048;  // 76,544 B (2 blocks/CU)
  hipFuncSetAttribute((const void*)(&lstm_rec<false>),
                      hipFuncAttributeMaxDynamicSharedMemorySize, (int)SMEM);
  hipFuncSetAttribute((const void*)(&lstm_rec<true>),
                      hipFuncAttributeMaxDynamicSharedMemorySize, (int)SMEM);

  // 1) prep: casts + splits + zero state/slots (1024 u32)
  {
    const size_t total = 37356544ull;
    const int blocks = (int)((total + 255) / 256);
    prep_kernel<<<blocks, 256, 0, stream>>>(ws, latent, inputs, mWih, mWhh, bWih, bWhh, linW);
  }
  // 2) measure input projection: xg = latent @ mWih^T + mb   [8192x4096], K=512
  gemm_bt_bias<<<2048, 256, 0, stream>>>(latb, mwihb, mb, xg, 512, 4096);

  // 3) measure LSTM (T=32), writes lat = tanh(h) (row-major)
  {
    const u16* a_whh = mwhhb; const float* a_xg = xg; const u16* a_wib = bwbb;
    const u16* a_inp = inpb;  const u16* a_lw = linwb; const float* a_lb = linb;
    u16* a_h0 = hm; u16* a_h1 = hm + Bz * Hz; u16* a_aux = latT;
    float* a_do = (float*)d_out; unsigned* a_ct = cs;
    void* margs[] = {&a_whh, &a_xg, &a_wib, &a_inp, &a_lw, &a_lb,
                     &a_h0, &a_h1, &a_aux, &a_do, &a_ct};
    hipError_t e = hipLaunchCooperativeKernel((const void*)(&lstm_rec<false>),
                                              dim3(512), dim3(256), margs, SMEM, stream);
    if (e != hipSuccess) {
      lstm_rec<false><<<512, 256, SMEM, stream>>>(mwhhb, xg, bwbb, inpb, linwb, linb,
                                                  hm, hm + Bz * Hz, latT,
                                                  (float*)d_out, cs);
    }
  }
  // 4) beat lat projection: xg = lat @ bWih[:, :1024]^T + bb   [8192x4096], K=1024
  gemm_bt_bias<<<2048, 256, 0, stream>>>(latT, bwab, bb, xg, 1024, 4096);

  // 5) beat LSTM (T=512) with fused input-projection + fused output linear
  {
    const u16* a_whh = bwhhb; const float* a_xg = xg; const u16* a_wib = bwbb;
    const u16* a_inp = inpb;  const u16* a_lw = linwb; const float* a_lb = linb;
    u16* a_h0 = hb; u16* a_h1 = hb + Bz * Hz; u16* a_aux = ring;
    float* a_do = (float*)d_out; unsigned* a_ct = cs + 512;
    void* bargs[] = {&a_whh, &a_xg, &a_wib, &a_inp, &a_lw, &a_lb,
                     &a_h0, &a_h1, &a_aux, &a_do, &a_ct};
    hipError_t e = hipLaunchCooperativeKernel((const void*)(&lstm_rec<true>),
                                              dim3(512), dim3(256), bargs, SMEM, stream);
    if (e != hipSuccess) {
      lstm_rec<true><<<512, 256, SMEM, stream>>>(bwhhb, xg, bwbb, inpb, linwb, linb,
                                                 hb, hb + Bz * Hz, ring,
                                                 (float*)d_out, cs + 512);
    }
  }
}